// Round 3
// baseline (2658.906 us; speedup 1.0000x reference)
//
#include <hip/hip_runtime.h>
#include <math.h>
#include <stdint.h>

typedef __bf16 bf16x8 __attribute__((ext_vector_type(8)));
typedef float f32x4 __attribute__((ext_vector_type(4)));

#define TWO_PI_F 6.28318530717958647692f
#define INV_4PI_F 0.079577471545947667884f

// ---------------------------------------------------------------------------
// Stream-ordered packed-weight layout: 176 contiguous 16KB chunks in exact
// consumption order. Chunk/phase t lives at ws + t*8192 (bf16 elements).
//   phases   0..63  : W1F  (K=2048 fwd)
//   phases  64..71  : W2F      72..79 : W3F      80..87 : W4F
//   phases  88..95  : W4B      96..103: W3B     104..111: W2B
//   phases 112..175 : W1B  (col-pair ct / ct+64 interleaved per chunk)
// ---------------------------------------------------------------------------
#define NPHASE 176
#define S_W2F 524288
#define S_W1B 917504
#define PACK_CHUNKS_TOTAL 180224   // 65536*2 + 8192*6 chunks of 8 bf16
#define PACK_BLOCKS 176            // PACK_CHUNKS_TOTAL / 1024

// async global->LDS, 16B per lane (global_load_lds_dwordx4)
typedef __attribute__((address_space(1))) const unsigned int GU32;
typedef __attribute__((address_space(3))) unsigned int LU32;
__device__ __forceinline__ void gll16(const __bf16* g, __bf16* l) {
  __builtin_amdgcn_global_load_lds((GU32*)(uintptr_t)(const void*)g,
                                   (LU32*)(unsigned int)(uintptr_t)(void*)l,
                                   16, 0, 0);
}

__device__ __forceinline__ float sin2pi(float t) {
  return __builtin_amdgcn_sinf(__builtin_amdgcn_fractf(t));
}
__device__ __forceinline__ float cos2pi(float t) {
  return __builtin_amdgcn_cosf(__builtin_amdgcn_fractf(t));
}

// ---------------------------------------------------------------------------
// Fused prep kernel: blocks [0,176) pack weights, blocks [176,432) Biot-Savart.
// ---------------------------------------------------------------------------
__launch_bounds__(1024)
__global__ void k_prep(const float* __restrict__ W1, const float* __restrict__ W2,
                       const float* __restrict__ W3, const float* __restrict__ W4,
                       const float* __restrict__ x, const float* __restrict__ bdry,
                       float* __restrict__ out, __bf16* __restrict__ ws,
                       int N, int M) {
  __shared__ float se[512 * 3];
  __shared__ float sm[512 * 3];
  __shared__ float red[3 * 256 * 3];

  if (blockIdx.x < PACK_BLOCKS) {
    int gid = blockIdx.x * 1024 + threadIdx.x;
    if (gid >= PACK_CHUNKS_TOTAL) return;
    const float* W; int n, q, ct, kc; bool bwd; long dstoff;
    if (gid < 65536) {                       // W1 forward: K=2048, N=256
      int c = gid; n = c & 15; q = (c >> 4) & 3; ct = (c >> 6) & 15; kc = c >> 10;
      W = W1; bwd = false; dstoff = (long)c * 8;
    } else if (gid < 131072) {               // W1 backward: K=256, N=2048
      int c = gid - 65536; n = c & 15; q = (c >> 4) & 3; kc = (c >> 6) & 7; ct = c >> 9;
      // interleave col-blocks ct and ct+64 so phase p = one contiguous 16KB chunk
      int newct = ((ct & 63) << 1) | (ct >> 6);
      long newc = (((long)newct * 8 + kc) * 4 + q) * 16 + n;
      W = W1; bwd = true; dstoff = S_W1B + newc * 8;
    } else {                                 // W2..W4 fwd/bwd: K=N=256
      int g = gid - 131072; int r = g >> 13; int c = g & 8191;
      n = c & 15; q = (c >> 4) & 3; ct = (c >> 6) & 15; kc = c >> 10;
      W = (r < 2) ? W2 : (r < 4) ? W3 : W4; bwd = (r & 1);
      int layer = r >> 1;
      int newr = bwd ? (5 - layer) : layer;  // region order W2F,W3F,W4F,W4B,W3B,W2B
      dstoff = S_W2F + (long)newr * 65536 + (long)c * 8;
    }
    int k0 = kc * 32 + q * 8;
    int ngl = ct * 16 + n;
    bf16x8 v;
    #pragma unroll
    for (int j = 0; j < 8; ++j) {
      float f = bwd ? W[ngl * 256 + (k0 + j)] : W[(k0 + j) * 256 + ngl];
      v[j] = (__bf16)f;
    }
    *(bf16x8*)(ws + dstoff) = v;
    return;
  }

  // ---- Biot-Savart: 256 points/block, 4 segment-chunks/point ----
  const int tid = threadIdx.x;
  for (int s = tid; s < M; s += 1024) {
    int sn = (s + 1 == M) ? 0 : s + 1;
    float b0 = bdry[s * 3 + 0], b1 = bdry[s * 3 + 1], b2 = bdry[s * 3 + 2];
    float c0 = bdry[sn * 3 + 0], c1 = bdry[sn * 3 + 1], c2 = bdry[sn * 3 + 2];
    se[s * 3 + 0] = c0 - b0; se[s * 3 + 1] = c1 - b1; se[s * 3 + 2] = c2 - b2;
    sm[s * 3 + 0] = 0.5f * (c0 + b0);
    sm[s * 3 + 1] = 0.5f * (c1 + b1);
    sm[s * 3 + 2] = 0.5f * (c2 + b2);
  }
  __syncthreads();
  const int p = tid & 255;
  const int q = tid >> 8;
  const int idx = (blockIdx.x - PACK_BLOCKS) * 256 + p;
  float x0 = fminf(fmaxf(x[idx * 3 + 0], -1.f), 1.f);
  float x1 = fminf(fmaxf(x[idx * 3 + 1], -1.f), 1.f);
  float x2 = fminf(fmaxf(x[idx * 3 + 2], -1.f), 1.f);
  const int mq = M >> 2;          // 128
  float a0 = 0.f, a1 = 0.f, a2 = 0.f;
  #pragma unroll 4
  for (int it = 0; it < mq; ++it) {
    int s = q * mq + it;
    float e0 = se[s * 3 + 0], e1 = se[s * 3 + 1], e2 = se[s * 3 + 2];
    float d0 = x0 - sm[s * 3 + 0], d1 = x1 - sm[s * 3 + 1], d2 = x2 - sm[s * 3 + 2];
    float r2 = d0 * d0 + d1 * d1 + d2 * d2;
    float inv = rsqrtf(r2);
    float inv3 = inv * inv * inv;
    float n0 = e1 * d2 - e2 * d1;
    float n1 = e2 * d0 - e0 * d2;
    float n2 = e0 * d1 - e1 * d0;
    a0 = fmaf(n0, inv3, a0); a1 = fmaf(n1, inv3, a1); a2 = fmaf(n2, inv3, a2);
  }
  if (q) {
    float* rp = &red[((q - 1) * 256 + p) * 3];
    rp[0] = a0; rp[1] = a1; rp[2] = a2;
  }
  __syncthreads();
  if (q == 0) {
    #pragma unroll
    for (int c = 0; c < 3; ++c) {
      const float* rp = &red[(c * 256 + p) * 3];
      a0 += rp[0]; a1 += rp[1]; a2 += rp[2];
    }
    float* alpha = out + (size_t)7 * N;
    alpha[idx * 3 + 0] = a0 * INV_4PI_F;
    alpha[idx * 3 + 1] = a1 * INV_4PI_F;
    alpha[idx * 3 + 2] = a2 * INV_4PI_F;
  }
}

// ---------------------------------------------------------------------------
// Fused MLP fwd + input-grad bwd. 256 thr = 4 waves, 16 rows/wave, 64 rows/WG.
// 176 uniform 16KB weight phases through a 3-buffer LDS ring:
//   phase t: ISSUE(t+2) -> compute(t) -> s_waitcnt vmcnt(4) -> s_barrier
// Counted vmcnt (never 0 in steady state) keeps 4-8 DMA loads in flight across
// every barrier (T3+T4). Brff lives in LDS so no per-phase global loads can
// force a vmcnt(0) drain. setprio(1) brackets each MFMA cluster (T5).
// LDS: 48KB ring + 16KB conv (time-shared 2 wave-groups) + 12KB Brff = 76KB
// -> 2 blocks/CU; VGPR ~124+AGPR (no spill; launch_bounds(256,2)).
// ---------------------------------------------------------------------------
__launch_bounds__(256, 2)
__global__ void k_mlp(const float* __restrict__ x, const float* __restrict__ Brff,
                      const float* __restrict__ b1, const float* __restrict__ b2,
                      const float* __restrict__ b3, const float* __restrict__ b4,
                      const float* __restrict__ W5, const float* __restrict__ b5,
                      const __bf16* __restrict__ wsw, float* __restrict__ out, int N) {
  __shared__ __attribute__((aligned(16))) __bf16 sW[3][8192];   // 48KB ring
  __shared__ __attribute__((aligned(16))) __bf16 sConv[8192];   // 16KB, 2 slots
  __shared__ __attribute__((aligned(16))) float  sBr[3072];     // 12KB RFF matrix

  const int tid  = threadIdx.x;
  const int wave = tid >> 6;
  const int lane = tid & 63;
  const int ml   = lane & 15;
  const int quad = lane >> 4;
  const int rowbase = blockIdx.x * 64 + wave * 16;
  const int cgrp  = wave >> 1;            // conv time-share group
  __bf16* conv = sConv + (wave & 1) * 4096;

  auto ISSUE = [&](int t) {               // stage chunk t into ring[t%3]
    const __bf16* src = wsw + (size_t)t * 8192;
    __bf16* dst = &sW[t % 3][0];
    #pragma unroll
    for (int r = 0; r < 4; ++r) {
      int idx = tid + r * 256;
      gll16(src + (size_t)idx * 8, dst + idx * 8);
    }
  };

  // ---- prologue: Brff -> LDS, x -> regs, kick phases 0 and 1 ----
  float4 bt0 = ((const float4*)Brff)[tid];
  float4 bt1 = ((const float4*)Brff)[tid + 256];
  float4 bt2 = ((const float4*)Brff)[tid + 512];

  float xa0, xa1, xa2;
  {
    const float* xp = x + (size_t)(rowbase + ml) * 3;
    xa0 = fminf(fmaxf(xp[0], -1.f), 1.f);
    xa1 = fminf(fmaxf(xp[1], -1.f), 1.f);
    xa2 = fminf(fmaxf(xp[2], -1.f), 1.f);
  }
  float xr[4][3];
  #pragma unroll
  for (int r = 0; r < 4; ++r) {
    const float* xp = x + (size_t)(rowbase + quad * 4 + r) * 3;
    #pragma unroll
    for (int i = 0; i < 3; ++i) xr[r][i] = fminf(fmaxf(xp[i], -1.f), 1.f);
  }

  ISSUE(0);
  ISSUE(1);
  ((float4*)sBr)[tid]       = bt0;
  ((float4*)sBr)[tid + 256] = bt1;
  ((float4*)sBr)[tid + 512] = bt2;

  f32x4 acc[16];
  bf16x8 h1f[8], h2f[8], h3f[8], gf[8];

  auto zero_acc = [&]() {
    #pragma unroll
    for (int ct = 0; ct < 16; ++ct) { f32x4 z = {0.f, 0.f, 0.f, 0.f}; acc[ct] = z; }
  };
  auto conv_widx = [&](int ct, int r) -> int {
    return (((ct >> 1) * 4 + ((ct & 1) << 1) + (ml >> 3)) * 16 + quad * 4 + r) * 8 + (ml & 7);
  };
  // acc (C-layout) -> conv LDS -> A-fragments, 2-group time-share, raw barriers
  auto xchg = [&](bf16x8* dst) {
    #pragma unroll
    for (int g = 0; g < 2; ++g) {
      if (cgrp == g) {
        #pragma unroll
        for (int ct = 0; ct < 16; ++ct)
          #pragma unroll
          for (int r = 0; r < 4; ++r)
            conv[conv_widx(ct, r)] = (__bf16)acc[ct][r];
        #pragma unroll
        for (int ks = 0; ks < 8; ++ks)
          dst[ks] = *(const bf16x8*)(conv + (ks * 4 + quad) * 128 + ml * 8);
        asm volatile("s_waitcnt lgkmcnt(0)" ::: "memory");  // reads done before slot reuse
      }
      __builtin_amdgcn_s_barrier();
    }
  };

  asm volatile("s_waitcnt vmcnt(4) lgkmcnt(0)" ::: "memory");  // chunk 0 + sBr ready
  __builtin_amdgcn_s_barrier();

  // ---- Forward L1: y(RFF) @ W1, phases 0..63 ----
  zero_acc();
  for (int kc = 0; kc < 64; ++kc) {
    ISSUE(kc + 2);
    const __bf16* wb = &sW[kc % 3][0];
    int cb = (kc * 32 + quad * 8) & 1023;
    bool issin = (kc < 32);
    bf16x8 af;
    #pragma unroll
    for (int j = 0; j < 8; ++j) {
      float t = xa0 * sBr[cb + j] + xa1 * sBr[1024 + cb + j] + xa2 * sBr[2048 + cb + j];
      af[j] = (__bf16)(issin ? sin2pi(t) : cos2pi(t));
    }
    __builtin_amdgcn_s_setprio(1);
    #pragma unroll
    for (int ct = 0; ct < 16; ++ct) {
      bf16x8 bfr = *(const bf16x8*)(wb + (ct * 4 + quad) * 128 + ml * 8);
      acc[ct] = __builtin_amdgcn_mfma_f32_16x16x32_bf16(af, bfr, acc[ct], 0, 0, 0);
    }
    __builtin_amdgcn_s_setprio(0);
    asm volatile("s_waitcnt vmcnt(4) lgkmcnt(0)" ::: "memory");
    __builtin_amdgcn_s_barrier();
  }

  auto epilogue_h = [&](const float* __restrict__ bias, bf16x8* hf) {
    #pragma unroll
    for (int ct = 0; ct < 16; ++ct) {
      float bcol = bias[ct * 16 + ml];
      #pragma unroll
      for (int r = 0; r < 4; ++r) {
        float z = acc[ct][r] + bcol;
        acc[ct][r] = fmaxf(z, 0.f) + __logf(1.f + __expf(-fabsf(z)));  // softplus
      }
    }
    xchg(hf);
  };

  // K=256,N=256 GEMM over phases t0..t0+7
  auto gemm256 = [&](const bf16x8* afr, int t0) {
    zero_acc();
    #pragma unroll
    for (int kc = 0; kc < 8; ++kc) {
      int t = t0 + kc;
      ISSUE(t + 2);
      const __bf16* wb = &sW[t % 3][0];
      __builtin_amdgcn_s_setprio(1);
      #pragma unroll
      for (int ct = 0; ct < 16; ++ct) {
        bf16x8 bfr = *(const bf16x8*)(wb + (ct * 4 + quad) * 128 + ml * 8);
        acc[ct] = __builtin_amdgcn_mfma_f32_16x16x32_bf16(afr[kc], bfr, acc[ct], 0, 0, 0);
      }
      __builtin_amdgcn_s_setprio(0);
      asm volatile("s_waitcnt vmcnt(4) lgkmcnt(0)" ::: "memory");
      __builtin_amdgcn_s_barrier();
    }
  };

  epilogue_h(b1, h1f);
  gemm256(h1f, 64);          // W2F
  epilogue_h(b2, h2f);
  gemm256(h2f, 72);          // W3F
  epilogue_h(b3, h3f);
  gemm256(h3f, 80);          // W4F

  // ---- L4 epilogue: f head + g4 = sigma(z4)*W5 ----
  {
    float fpart[4] = {0.f, 0.f, 0.f, 0.f};
    #pragma unroll
    for (int ct = 0; ct < 16; ++ct) {
      float bcol = b4[ct * 16 + ml];
      float w5   = W5[ct * 16 + ml];
      #pragma unroll
      for (int r = 0; r < 4; ++r) {
        float z = acc[ct][r] + bcol;
        float ez = __expf(-fabsf(z));
        float sp = fmaxf(z, 0.f) + __logf(1.f + ez);
        float sig = (z >= 0.f) ? 1.f / (1.f + ez) : ez / (1.f + ez);
        fpart[r] += sp * w5;
        acc[ct][r] = sig * w5;
      }
    }
    #pragma unroll
    for (int r = 0; r < 4; ++r) {
      float v = fpart[r];
      #pragma unroll
      for (int m = 1; m < 16; m <<= 1) v += __shfl_xor(v, m, 64);
      if (ml == 0) out[rowbase + quad * 4 + r] = v + b5[0];
    }
    xchg(gf);
  }

  // ---- Backward: g_{l-1} = (g_l @ W_l^T) * (1 - exp(-h_{l-1})) ----
  auto epilogue_g = [&](const bf16x8* hf) {
    xchg(gf);
    #pragma unroll
    for (int ks = 0; ks < 8; ++ks) {
      #pragma unroll
      for (int j = 0; j < 8; ++j) {
        float gp = (float)gf[ks][j];
        float h  = (float)hf[ks][j];
        gf[ks][j] = (__bf16)(gp * (1.f - __expf(-h)));
      }
    }
  };

  gemm256(gf, 88);  epilogue_g(h3f);   // W4B
  gemm256(gf, 96);  epilogue_g(h2f);   // W3B
  gemm256(gf, 104); epilogue_g(h1f);   // W2B

  // ---- Backward L1: phases 112..175, cols paired (c, c+1024) ----
  float dxa[4][3];
  #pragma unroll
  for (int r = 0; r < 4; ++r) { dxa[r][0] = 0.f; dxa[r][1] = 0.f; dxa[r][2] = 0.f; }

  for (int p = 0; p < 64; ++p) {
    int t = 112 + p;
    if (p < 62) ISSUE(t + 2);
    const __bf16* wb = &sW[t % 3][0];
    f32x4 aA = {0.f, 0.f, 0.f, 0.f}, aB = {0.f, 0.f, 0.f, 0.f};
    __builtin_amdgcn_s_setprio(1);
    #pragma unroll
    for (int ks = 0; ks < 8; ++ks) {
      bf16x8 bA = *(const bf16x8*)(wb + (ks * 4 + quad) * 128 + ml * 8);
      bf16x8 bB = *(const bf16x8*)(wb + 4096 + (ks * 4 + quad) * 128 + ml * 8);
      aA = __builtin_amdgcn_mfma_f32_16x16x32_bf16(gf[ks], bA, aA, 0, 0, 0);
      aB = __builtin_amdgcn_mfma_f32_16x16x32_bf16(gf[ks], bB, aB, 0, 0, 0);
    }
    __builtin_amdgcn_s_setprio(0);
    int c = p * 16 + ml;
    float B0 = sBr[c], B1 = sBr[1024 + c], B2 = sBr[2048 + c];
    #pragma unroll
    for (int r = 0; r < 4; ++r) {
      float t2 = xr[r][0] * B0 + xr[r][1] * B1 + xr[r][2] * B2;
      float tf = __builtin_amdgcn_fractf(t2);
      float sn = __builtin_amdgcn_sinf(tf);
      float cs = __builtin_amdgcn_cosf(tf);
      float dp = aA[r] * cs - aB[r] * sn;
      dxa[r][0] = fmaf(dp, B0, dxa[r][0]);
      dxa[r][1] = fmaf(dp, B1, dxa[r][1]);
      dxa[r][2] = fmaf(dp, B2, dxa[r][2]);
    }
    if (p < 62)       asm volatile("s_waitcnt vmcnt(4) lgkmcnt(0)" ::: "memory");
    else if (p == 62) asm volatile("s_waitcnt vmcnt(0) lgkmcnt(0)" ::: "memory");
    if (p < 63) __builtin_amdgcn_s_barrier();
  }

  #pragma unroll
  for (int r = 0; r < 4; ++r) {
    #pragma unroll
    for (int i = 0; i < 3; ++i) {
      float v = dxa[r][i] * TWO_PI_F;
      #pragma unroll
      for (int m = 1; m < 16; m <<= 1) v += __shfl_xor(v, m, 64);
      if (ml == 0) {
        int row = rowbase + quad * 4 + r;
        out[(size_t)4 * N + row * 3 + i] = v;                                   // df
        out[(size_t)N + row * 3 + i] = v + out[(size_t)7 * N + row * 3 + i];    // current
      }
    }
  }
}

extern "C" void kernel_launch(void* const* d_in, const int* in_sizes, int n_in,
                              void* d_out, int out_size, void* d_ws, size_t ws_size,
                              hipStream_t stream) {
  const float* x    = (const float*)d_in[0];
  const float* bdry = (const float*)d_in[1];
  const float* Brff = (const float*)d_in[2];
  const float* W1   = (const float*)d_in[3];
  const float* b1   = (const float*)d_in[4];
  const float* W2   = (const float*)d_in[5];
  const float* b2   = (const float*)d_in[6];
  const float* W3   = (const float*)d_in[7];
  const float* b3   = (const float*)d_in[8];
  const float* W4   = (const float*)d_in[9];
  const float* b4   = (const float*)d_in[10];
  const float* W5   = (const float*)d_in[11];
  const float* b5   = (const float*)d_in[12];
  float* out = (float*)d_out;
  __bf16* ws = (__bf16*)d_ws;
  int N = in_sizes[0] / 3;   // 65536
  int M = in_sizes[1] / 3;   // 512

  k_prep<<<PACK_BLOCKS + N / 256, 1024, 0, stream>>>(W1, W2, W3, W4, x, bdry, out, ws, N, M);
  k_mlp<<<N / 64, 256, 0, stream>>>(x, Brff, b1, b2, b3, b4, W5, b5, ws, out, N);
}

// Round 4
// 2515.169 us; speedup vs baseline: 1.0571x; 1.0571x over previous
//
#include <hip/hip_runtime.h>
#include <math.h>
#include <stdint.h>

typedef __bf16 bf16x8 __attribute__((ext_vector_type(8)));
typedef float f32x4 __attribute__((ext_vector_type(4)));

#define TWO_PI_F 6.28318530717958647692f
#define INV_4PI_F 0.079577471545947667884f

// ---------------------------------------------------------------------------
// Stream-ordered packed-weight layout: 176 contiguous 16KB chunks in exact
// consumption order. Chunk/phase t lives at ws + t*8192 (bf16 elements).
//   phases   0..63  : W1F  (K=2048 fwd)
//   phases  64..71  : W2F      72..79 : W3F      80..87 : W4F
//   phases  88..95  : W4B      96..103: W3B     104..111: W2B
//   phases 112..175 : W1B  (col-pair ct / ct+64 interleaved per chunk)
// ---------------------------------------------------------------------------
#define NPHASE 176
#define S_W2F 524288
#define S_W1B 917504
#define PACK_CHUNKS_TOTAL 180224   // 65536*2 + 8192*6 chunks of 8 bf16
#define PACK_BLOCKS 176            // PACK_CHUNKS_TOTAL / 1024

// async global->LDS, 16B per lane (global_load_lds_dwordx4)
typedef __attribute__((address_space(1))) const unsigned int GU32;
typedef __attribute__((address_space(3))) unsigned int LU32;
__device__ __forceinline__ void gll16(const __bf16* g, __bf16* l) {
  __builtin_amdgcn_global_load_lds((GU32*)(uintptr_t)(const void*)g,
                                   (LU32*)(unsigned int)(uintptr_t)(void*)l,
                                   16, 0, 0);
}

__device__ __forceinline__ float sin2pi(float t) {
  return __builtin_amdgcn_sinf(__builtin_amdgcn_fractf(t));
}
__device__ __forceinline__ float cos2pi(float t) {
  return __builtin_amdgcn_cosf(__builtin_amdgcn_fractf(t));
}

// ---------------------------------------------------------------------------
// Fused prep kernel: blocks [0,176) pack weights, blocks [176,432) Biot-Savart.
// ---------------------------------------------------------------------------
__launch_bounds__(1024)
__global__ void k_prep(const float* __restrict__ W1, const float* __restrict__ W2,
                       const float* __restrict__ W3, const float* __restrict__ W4,
                       const float* __restrict__ x, const float* __restrict__ bdry,
                       float* __restrict__ out, __bf16* __restrict__ ws,
                       int N, int M) {
  __shared__ float se[512 * 3];
  __shared__ float sm[512 * 3];
  __shared__ float red[3 * 256 * 3];

  if (blockIdx.x < PACK_BLOCKS) {
    int gid = blockIdx.x * 1024 + threadIdx.x;
    if (gid >= PACK_CHUNKS_TOTAL) return;
    const float* W; int n, q, ct, kc; bool bwd; long dstoff;
    if (gid < 65536) {                       // W1 forward: K=2048, N=256
      int c = gid; n = c & 15; q = (c >> 4) & 3; ct = (c >> 6) & 15; kc = c >> 10;
      W = W1; bwd = false; dstoff = (long)c * 8;
    } else if (gid < 131072) {               // W1 backward: K=256, N=2048
      int c = gid - 65536; n = c & 15; q = (c >> 4) & 3; kc = (c >> 6) & 7; ct = c >> 9;
      // interleave col-blocks ct and ct+64 so phase p = one contiguous 16KB chunk
      int newct = ((ct & 63) << 1) | (ct >> 6);
      long newc = (((long)newct * 8 + kc) * 4 + q) * 16 + n;
      W = W1; bwd = true; dstoff = S_W1B + newc * 8;
    } else {                                 // W2..W4 fwd/bwd: K=N=256
      int g = gid - 131072; int r = g >> 13; int c = g & 8191;
      n = c & 15; q = (c >> 4) & 3; ct = (c >> 6) & 15; kc = c >> 10;
      W = (r < 2) ? W2 : (r < 4) ? W3 : W4; bwd = (r & 1);
      int layer = r >> 1;
      int newr = bwd ? (5 - layer) : layer;  // region order W2F,W3F,W4F,W4B,W3B,W2B
      dstoff = S_W2F + (long)newr * 65536 + (long)c * 8;
    }
    int k0 = kc * 32 + q * 8;
    int ngl = ct * 16 + n;
    bf16x8 v;
    #pragma unroll
    for (int j = 0; j < 8; ++j) {
      float f = bwd ? W[ngl * 256 + (k0 + j)] : W[(k0 + j) * 256 + ngl];
      v[j] = (__bf16)f;
    }
    *(bf16x8*)(ws + dstoff) = v;
    return;
  }

  // ---- Biot-Savart: 256 points/block, 4 segment-chunks/point ----
  const int tid = threadIdx.x;
  for (int s = tid; s < M; s += 1024) {
    int sn = (s + 1 == M) ? 0 : s + 1;
    float b0 = bdry[s * 3 + 0], b1 = bdry[s * 3 + 1], b2 = bdry[s * 3 + 2];
    float c0 = bdry[sn * 3 + 0], c1 = bdry[sn * 3 + 1], c2 = bdry[sn * 3 + 2];
    se[s * 3 + 0] = c0 - b0; se[s * 3 + 1] = c1 - b1; se[s * 3 + 2] = c2 - b2;
    sm[s * 3 + 0] = 0.5f * (c0 + b0);
    sm[s * 3 + 1] = 0.5f * (c1 + b1);
    sm[s * 3 + 2] = 0.5f * (c2 + b2);
  }
  __syncthreads();
  const int p = tid & 255;
  const int q = tid >> 8;
  const int idx = (blockIdx.x - PACK_BLOCKS) * 256 + p;
  float x0 = fminf(fmaxf(x[idx * 3 + 0], -1.f), 1.f);
  float x1 = fminf(fmaxf(x[idx * 3 + 1], -1.f), 1.f);
  float x2 = fminf(fmaxf(x[idx * 3 + 2], -1.f), 1.f);
  const int mq = M >> 2;          // 128
  float a0 = 0.f, a1 = 0.f, a2 = 0.f;
  #pragma unroll 4
  for (int it = 0; it < mq; ++it) {
    int s = q * mq + it;
    float e0 = se[s * 3 + 0], e1 = se[s * 3 + 1], e2 = se[s * 3 + 2];
    float d0 = x0 - sm[s * 3 + 0], d1 = x1 - sm[s * 3 + 1], d2 = x2 - sm[s * 3 + 2];
    float r2 = d0 * d0 + d1 * d1 + d2 * d2;
    float inv = rsqrtf(r2);
    float inv3 = inv * inv * inv;
    float n0 = e1 * d2 - e2 * d1;
    float n1 = e2 * d0 - e0 * d2;
    float n2 = e0 * d1 - e1 * d0;
    a0 = fmaf(n0, inv3, a0); a1 = fmaf(n1, inv3, a1); a2 = fmaf(n2, inv3, a2);
  }
  if (q) {
    float* rp = &red[((q - 1) * 256 + p) * 3];
    rp[0] = a0; rp[1] = a1; rp[2] = a2;
  }
  __syncthreads();
  if (q == 0) {
    #pragma unroll
    for (int c = 0; c < 3; ++c) {
      const float* rp = &red[(c * 256 + p) * 3];
      a0 += rp[0]; a1 += rp[1]; a2 += rp[2];
    }
    float* alpha = out + (size_t)7 * N;
    alpha[idx * 3 + 0] = a0 * INV_4PI_F;
    alpha[idx * 3 + 1] = a1 * INV_4PI_F;
    alpha[idx * 3 + 2] = a2 * INV_4PI_F;
  }
}

// ---------------------------------------------------------------------------
// Fused MLP fwd + input-grad bwd. 256 thr = 4 waves, 16 rows/wave, 64 rows/WG.
// 176 uniform 16KB weight phases through a 3-buffer LDS ring:
//   phase t: ISSUE(t+2) -> compute(t) -> s_waitcnt vmcnt(4) -> s_barrier
// Counted vmcnt (never 0 in steady state) keeps 4-8 DMA loads in flight across
// every barrier. NO "memory" clobbers anywhere (round-3 lesson: they block
// mem2reg of the address-taken h-arrays -> 6.8GB scratch traffic); ordering is
// pinned with sched_barrier(0) instead. All in-loop operands (Brff, biases,
// W5, b5) live in LDS so no global load can force a vmcnt(0) drain mid-stream.
// LDS: 48KB ring + 8KB conv (4-wave time-share) + 12KB Brff + 5KB bias = 73KB
// -> 2 blocks/CU. Register state (acc 64 AGPR + 4x bf16x8[8] = 128 VGPR) fits
// the 2-wave/EU budget with no spill (round-0 codegen).
// ---------------------------------------------------------------------------
__launch_bounds__(256, 2)
__global__ void k_mlp(const float* __restrict__ x, const float* __restrict__ Brff,
                      const float* __restrict__ b1, const float* __restrict__ b2,
                      const float* __restrict__ b3, const float* __restrict__ b4,
                      const float* __restrict__ W5, const float* __restrict__ b5,
                      const __bf16* __restrict__ wsw, float* __restrict__ out, int N) {
  __shared__ __attribute__((aligned(16))) __bf16 sW[3][8192];   // 48KB ring
  __shared__ __attribute__((aligned(16))) __bf16 sConv[4096];   // 8KB, 1 slot
  __shared__ __attribute__((aligned(16))) float  sBr[3072];     // 12KB RFF matrix
  __shared__ __attribute__((aligned(16))) float  sBias[1284];   // b1..b4,W5,b5

  const int tid  = threadIdx.x;
  const int wave = tid >> 6;
  const int lane = tid & 63;
  const int ml   = lane & 15;
  const int quad = lane >> 4;
  const int rowbase = blockIdx.x * 64 + wave * 16;

  auto ISSUE = [&](int t) {               // stage chunk t into ring[t%3]
    const __bf16* src = wsw + (size_t)t * 8192;
    __bf16* dst = &sW[t % 3][0];
    #pragma unroll
    for (int r = 0; r < 4; ++r) {
      int idx = tid + r * 256;
      gll16(src + (size_t)idx * 8, dst + idx * 8);
    }
  };

  // ---- prologue: Brff + biases -> LDS, x -> regs, kick phases 0 and 1 ----
  float4 bt0 = ((const float4*)Brff)[tid];
  float4 bt1 = ((const float4*)Brff)[tid + 256];
  float4 bt2 = ((const float4*)Brff)[tid + 512];
  float bb1 = b1[tid], bb2 = b2[tid], bb3 = b3[tid], bb4 = b4[tid];
  float w5v = W5[tid];

  float xa0, xa1, xa2;
  {
    const float* xp = x + (size_t)(rowbase + ml) * 3;
    xa0 = fminf(fmaxf(xp[0], -1.f), 1.f);
    xa1 = fminf(fmaxf(xp[1], -1.f), 1.f);
    xa2 = fminf(fmaxf(xp[2], -1.f), 1.f);
  }
  float xr[4][3];
  #pragma unroll
  for (int r = 0; r < 4; ++r) {
    const float* xp = x + (size_t)(rowbase + quad * 4 + r) * 3;
    #pragma unroll
    for (int i = 0; i < 3; ++i) xr[r][i] = fminf(fmaxf(xp[i], -1.f), 1.f);
  }

  ISSUE(0);
  ISSUE(1);
  ((float4*)sBr)[tid]       = bt0;
  ((float4*)sBr)[tid + 256] = bt1;
  ((float4*)sBr)[tid + 512] = bt2;
  sBias[tid]        = bb1;
  sBias[256 + tid]  = bb2;
  sBias[512 + tid]  = bb3;
  sBias[768 + tid]  = bb4;
  sBias[1024 + tid] = w5v;
  if (tid == 0) sBias[1280] = b5[0];

  f32x4 acc[16];
  bf16x8 h1f[8], h2f[8], h3f[8], gf[8];

  auto zero_acc = [&]() {
    #pragma unroll
    for (int ct = 0; ct < 16; ++ct) { f32x4 z = {0.f, 0.f, 0.f, 0.f}; acc[ct] = z; }
  };
  auto conv_widx = [&](int ct, int r) -> int {
    return (((ct >> 1) * 4 + ((ct & 1) << 1) + (ml >> 3)) * 16 + quad * 4 + r) * 8 + (ml & 7);
  };
  // acc (C-layout) -> conv LDS -> A-fragments; 4-wave time-share of one slot
  auto xchg = [&](bf16x8* dst) {
    #pragma unroll
    for (int g = 0; g < 4; ++g) {
      if (wave == g) {
        #pragma unroll
        for (int ct = 0; ct < 16; ++ct)
          #pragma unroll
          for (int r = 0; r < 4; ++r)
            sConv[conv_widx(ct, r)] = (__bf16)acc[ct][r];
        asm volatile("s_waitcnt lgkmcnt(0)");
        __builtin_amdgcn_sched_barrier(0);
        #pragma unroll
        for (int ks = 0; ks < 8; ++ks)
          dst[ks] = *(const bf16x8*)(sConv + (ks * 4 + quad) * 128 + ml * 8);
        asm volatile("s_waitcnt lgkmcnt(0)");
        __builtin_amdgcn_sched_barrier(0);
      }
      __builtin_amdgcn_s_barrier();
    }
  };

  // phase-boundary wait: pin both sides, counted vmcnt, single barrier
  auto phase_wait4 = [&]() {
    __builtin_amdgcn_sched_barrier(0);
    asm volatile("s_waitcnt vmcnt(4) lgkmcnt(0)");
    __builtin_amdgcn_sched_barrier(0);
    __builtin_amdgcn_s_barrier();
  };

  phase_wait4();   // chunk 0 + sBr/sBias resident (chunk 1 still in flight)

  // ---- Forward L1: y(RFF) @ W1, phases 0..63 ----
  zero_acc();
  for (int kc = 0; kc < 64; ++kc) {
    ISSUE(kc + 2);
    const __bf16* wb = &sW[kc % 3][0];
    int cb = (kc * 32 + quad * 8) & 1023;
    bool issin = (kc < 32);
    bf16x8 af;
    #pragma unroll
    for (int j = 0; j < 8; ++j) {
      float t = xa0 * sBr[cb + j] + xa1 * sBr[1024 + cb + j] + xa2 * sBr[2048 + cb + j];
      af[j] = (__bf16)(issin ? sin2pi(t) : cos2pi(t));
    }
    __builtin_amdgcn_s_setprio(1);
    #pragma unroll
    for (int ct = 0; ct < 16; ++ct) {
      bf16x8 bfr = *(const bf16x8*)(wb + (ct * 4 + quad) * 128 + ml * 8);
      acc[ct] = __builtin_amdgcn_mfma_f32_16x16x32_bf16(af, bfr, acc[ct], 0, 0, 0);
    }
    __builtin_amdgcn_s_setprio(0);
    phase_wait4();
  }

  auto epilogue_h = [&](int boff, bf16x8* hf) {
    #pragma unroll
    for (int ct = 0; ct < 16; ++ct) {
      float bcol = sBias[boff + ct * 16 + ml];
      #pragma unroll
      for (int r = 0; r < 4; ++r) {
        float z = acc[ct][r] + bcol;
        acc[ct][r] = fmaxf(z, 0.f) + __logf(1.f + __expf(-fabsf(z)));  // softplus
      }
    }
    xchg(hf);
  };

  // K=256,N=256 GEMM over phases t0..t0+7
  auto gemm256 = [&](const bf16x8* afr, int t0) {
    zero_acc();
    #pragma unroll
    for (int kc = 0; kc < 8; ++kc) {
      int t = t0 + kc;
      ISSUE(t + 2);
      const __bf16* wb = &sW[t % 3][0];
      __builtin_amdgcn_s_setprio(1);
      #pragma unroll
      for (int ct = 0; ct < 16; ++ct) {
        bf16x8 bfr = *(const bf16x8*)(wb + (ct * 4 + quad) * 128 + ml * 8);
        acc[ct] = __builtin_amdgcn_mfma_f32_16x16x32_bf16(afr[kc], bfr, acc[ct], 0, 0, 0);
      }
      __builtin_amdgcn_s_setprio(0);
      phase_wait4();
    }
  };

  epilogue_h(0, h1f);
  gemm256(h1f, 64);          // W2F
  epilogue_h(256, h2f);
  gemm256(h2f, 72);          // W3F
  epilogue_h(512, h3f);
  gemm256(h3f, 80);          // W4F

  // ---- L4 epilogue: f head + g4 = sigma(z4)*W5 ----
  {
    float fpart[4] = {0.f, 0.f, 0.f, 0.f};
    #pragma unroll
    for (int ct = 0; ct < 16; ++ct) {
      float bcol = sBias[768 + ct * 16 + ml];
      float w5   = sBias[1024 + ct * 16 + ml];
      #pragma unroll
      for (int r = 0; r < 4; ++r) {
        float z = acc[ct][r] + bcol;
        float ez = __expf(-fabsf(z));
        float sp = fmaxf(z, 0.f) + __logf(1.f + ez);
        float sig = (z >= 0.f) ? 1.f / (1.f + ez) : ez / (1.f + ez);
        fpart[r] += sp * w5;
        acc[ct][r] = sig * w5;
      }
    }
    float b5v = sBias[1280];
    #pragma unroll
    for (int r = 0; r < 4; ++r) {
      float v = fpart[r];
      #pragma unroll
      for (int m = 1; m < 16; m <<= 1) v += __shfl_xor(v, m, 64);
      if (ml == 0) out[rowbase + quad * 4 + r] = v + b5v;
    }
    xchg(gf);
  }

  // ---- Backward: g_{l-1} = (g_l @ W_l^T) * (1 - exp(-h_{l-1})) ----
  auto epilogue_g = [&](const bf16x8* hf) {
    xchg(gf);
    #pragma unroll
    for (int ks = 0; ks < 8; ++ks) {
      #pragma unroll
      for (int j = 0; j < 8; ++j) {
        float gp = (float)gf[ks][j];
        float h  = (float)hf[ks][j];
        gf[ks][j] = (__bf16)(gp * (1.f - __expf(-h)));
      }
    }
  };

  gemm256(gf, 88);  epilogue_g(h3f);   // W4B
  gemm256(gf, 96);  epilogue_g(h2f);   // W3B
  gemm256(gf, 104); epilogue_g(h1f);   // W2B

  // ---- Backward L1: phases 112..175, cols paired (c, c+1024) ----
  float dxa[4][3];
  #pragma unroll
  for (int r = 0; r < 4; ++r) { dxa[r][0] = 0.f; dxa[r][1] = 0.f; dxa[r][2] = 0.f; }

  for (int p = 0; p < 64; ++p) {
    int t = 112 + p;
    if (p < 62) ISSUE(t + 2);
    const __bf16* wb = &sW[t % 3][0];
    f32x4 aA = {0.f, 0.f, 0.f, 0.f}, aB = {0.f, 0.f, 0.f, 0.f};
    __builtin_amdgcn_s_setprio(1);
    #pragma unroll
    for (int ks = 0; ks < 8; ++ks) {
      bf16x8 bA = *(const bf16x8*)(wb + (ks * 4 + quad) * 128 + ml * 8);
      bf16x8 bB = *(const bf16x8*)(wb + 4096 + (ks * 4 + quad) * 128 + ml * 8);
      aA = __builtin_amdgcn_mfma_f32_16x16x32_bf16(gf[ks], bA, aA, 0, 0, 0);
      aB = __builtin_amdgcn_mfma_f32_16x16x32_bf16(gf[ks], bB, aB, 0, 0, 0);
    }
    __builtin_amdgcn_s_setprio(0);
    int c = p * 16 + ml;
    float B0 = sBr[c], B1 = sBr[1024 + c], B2 = sBr[2048 + c];
    #pragma unroll
    for (int r = 0; r < 4; ++r) {
      float t2 = xr[r][0] * B0 + xr[r][1] * B1 + xr[r][2] * B2;
      float tf = __builtin_amdgcn_fractf(t2);
      float sn = __builtin_amdgcn_sinf(tf);
      float cs = __builtin_amdgcn_cosf(tf);
      float dp = aA[r] * cs - aB[r] * sn;
      dxa[r][0] = fmaf(dp, B0, dxa[r][0]);
      dxa[r][1] = fmaf(dp, B1, dxa[r][1]);
      dxa[r][2] = fmaf(dp, B2, dxa[r][2]);
    }
    if (p < 62) {
      phase_wait4();
    } else if (p == 62) {
      __builtin_amdgcn_sched_barrier(0);
      asm volatile("s_waitcnt vmcnt(0) lgkmcnt(0)");
      __builtin_amdgcn_sched_barrier(0);
      __builtin_amdgcn_s_barrier();
    }
  }

  #pragma unroll
  for (int r = 0; r < 4; ++r) {
    #pragma unroll
    for (int i = 0; i < 3; ++i) {
      float v = dxa[r][i] * TWO_PI_F;
      #pragma unroll
      for (int m = 1; m < 16; m <<= 1) v += __shfl_xor(v, m, 64);
      if (ml == 0) {
        int row = rowbase + quad * 4 + r;
        out[(size_t)4 * N + row * 3 + i] = v;                                   // df
        out[(size_t)N + row * 3 + i] = v + out[(size_t)7 * N + row * 3 + i];    // current
      }
    }
  }
}

extern "C" void kernel_launch(void* const* d_in, const int* in_sizes, int n_in,
                              void* d_out, int out_size, void* d_ws, size_t ws_size,
                              hipStream_t stream) {
  const float* x    = (const float*)d_in[0];
  const float* bdry = (const float*)d_in[1];
  const float* Brff = (const float*)d_in[2];
  const float* W1   = (const float*)d_in[3];
  const float* b1   = (const float*)d_in[4];
  const float* W2   = (const float*)d_in[5];
  const float* b2   = (const float*)d_in[6];
  const float* W3   = (const float*)d_in[7];
  const float* b3   = (const float*)d_in[8];
  const float* W4   = (const float*)d_in[9];
  const float* b4   = (const float*)d_in[10];
  const float* W5   = (const float*)d_in[11];
  const float* b5   = (const float*)d_in[12];
  float* out = (float*)d_out;
  __bf16* ws = (__bf16*)d_ws;
  int N = in_sizes[0] / 3;   // 65536
  int M = in_sizes[1] / 3;   // 512

  k_prep<<<PACK_BLOCKS + N / 256, 1024, 0, stream>>>(W1, W2, W3, W4, x, bdry, out, ws, N, M);
  k_mlp<<<N / 64, 256, 0, stream>>>(x, Brff, b1, b2, b3, b4, W5, b5, ws, out, N);
}

// Round 5
// 414.018 us; speedup vs baseline: 6.4222x; 6.0750x over previous
//
#include <hip/hip_runtime.h>
#include <math.h>
#include <stdint.h>

typedef __bf16 bf16x8 __attribute__((ext_vector_type(8)));
typedef float f32x4 __attribute__((ext_vector_type(4)));
typedef unsigned int uint4v __attribute__((ext_vector_type(4)));

#define TWO_PI_F 6.28318530717958647692f
#define INV_4PI_F 0.079577471545947667884f

// ---------------------------------------------------------------------------
// Stream-ordered packed-weight layout: 176 contiguous 16KB chunks in exact
// consumption order (phase t at ws + t*8192 bf16 elems):
//   0..63 W1F | 64..71 W2F | 72..79 W3F | 80..87 W4F
//   88..95 W4B | 96..103 W3B | 104..111 W2B | 112..175 W1B (col c,c+1024 pairs)
// h-stash (NT=2 path) lives after the weights at H_OFF.
// ---------------------------------------------------------------------------
#define NPHASE 176
#define S_W2F 524288
#define S_W1B 917504
#define PACK_CHUNKS_TOTAL 180224   // 65536*2 + 8192*6 chunks of 8 bf16
#define PACK_BLOCKS 176
#define H_OFF 1441792ll            // 176*8192 bf16 elems (end of weights)
#define H_STRIDE 16777216ll        // 65536*256 bf16 elems per stashed layer

__device__ __forceinline__ float sin2pi(float t) {
  return __builtin_amdgcn_sinf(__builtin_amdgcn_fractf(t));
}
__device__ __forceinline__ float cos2pi(float t) {
  return __builtin_amdgcn_cosf(__builtin_amdgcn_fractf(t));
}

// ---------------------------------------------------------------------------
// Fused prep: blocks [0,176) pack weights, blocks [176,432) Biot-Savart.
// (verbatim from the passing round-3/4 version)
// ---------------------------------------------------------------------------
__launch_bounds__(1024)
__global__ void k_prep(const float* __restrict__ W1, const float* __restrict__ W2,
                       const float* __restrict__ W3, const float* __restrict__ W4,
                       const float* __restrict__ x, const float* __restrict__ bdry,
                       float* __restrict__ out, __bf16* __restrict__ ws,
                       int N, int M) {
  __shared__ float se[512 * 3];
  __shared__ float sm[512 * 3];
  __shared__ float red[3 * 256 * 3];

  if (blockIdx.x < PACK_BLOCKS) {
    int gid = blockIdx.x * 1024 + threadIdx.x;
    if (gid >= PACK_CHUNKS_TOTAL) return;
    const float* W; int n, q, ct, kc; bool bwd; long dstoff;
    if (gid < 65536) {                       // W1 forward: K=2048, N=256
      int c = gid; n = c & 15; q = (c >> 4) & 3; ct = (c >> 6) & 15; kc = c >> 10;
      W = W1; bwd = false; dstoff = (long)c * 8;
    } else if (gid < 131072) {               // W1 backward: K=256, N=2048
      int c = gid - 65536; n = c & 15; q = (c >> 4) & 3; kc = (c >> 6) & 7; ct = c >> 9;
      int newct = ((ct & 63) << 1) | (ct >> 6);
      long newc = (((long)newct * 8 + kc) * 4 + q) * 16 + n;
      W = W1; bwd = true; dstoff = S_W1B + newc * 8;
    } else {                                 // W2..W4 fwd/bwd: K=N=256
      int g = gid - 131072; int r = g >> 13; int c = g & 8191;
      n = c & 15; q = (c >> 4) & 3; ct = (c >> 6) & 15; kc = c >> 10;
      W = (r < 2) ? W2 : (r < 4) ? W3 : W4; bwd = (r & 1);
      int layer = r >> 1;
      int newr = bwd ? (5 - layer) : layer;  // W2F,W3F,W4F,W4B,W3B,W2B
      dstoff = S_W2F + (long)newr * 65536 + (long)c * 8;
    }
    int k0 = kc * 32 + q * 8;
    int ngl = ct * 16 + n;
    bf16x8 v;
    #pragma unroll
    for (int j = 0; j < 8; ++j) {
      float f = bwd ? W[ngl * 256 + (k0 + j)] : W[(k0 + j) * 256 + ngl];
      v[j] = (__bf16)f;
    }
    *(bf16x8*)(ws + dstoff) = v;
    return;
  }

  const int tid = threadIdx.x;
  for (int s = tid; s < M; s += 1024) {
    int sn = (s + 1 == M) ? 0 : s + 1;
    float b0 = bdry[s * 3 + 0], b1 = bdry[s * 3 + 1], b2 = bdry[s * 3 + 2];
    float c0 = bdry[sn * 3 + 0], c1 = bdry[sn * 3 + 1], c2 = bdry[sn * 3 + 2];
    se[s * 3 + 0] = c0 - b0; se[s * 3 + 1] = c1 - b1; se[s * 3 + 2] = c2 - b2;
    sm[s * 3 + 0] = 0.5f * (c0 + b0);
    sm[s * 3 + 1] = 0.5f * (c1 + b1);
    sm[s * 3 + 2] = 0.5f * (c2 + b2);
  }
  __syncthreads();
  const int p = tid & 255;
  const int q = tid >> 8;
  const int idx = (blockIdx.x - PACK_BLOCKS) * 256 + p;
  float x0 = fminf(fmaxf(x[idx * 3 + 0], -1.f), 1.f);
  float x1 = fminf(fmaxf(x[idx * 3 + 1], -1.f), 1.f);
  float x2 = fminf(fmaxf(x[idx * 3 + 2], -1.f), 1.f);
  const int mq = M >> 2;
  float a0 = 0.f, a1 = 0.f, a2 = 0.f;
  #pragma unroll 4
  for (int it = 0; it < mq; ++it) {
    int s = q * mq + it;
    float e0 = se[s * 3 + 0], e1 = se[s * 3 + 1], e2 = se[s * 3 + 2];
    float d0 = x0 - sm[s * 3 + 0], d1 = x1 - sm[s * 3 + 1], d2 = x2 - sm[s * 3 + 2];
    float r2 = d0 * d0 + d1 * d1 + d2 * d2;
    float inv = rsqrtf(r2);
    float inv3 = inv * inv * inv;
    float n0 = e1 * d2 - e2 * d1;
    float n1 = e2 * d0 - e0 * d2;
    float n2 = e0 * d1 - e1 * d0;
    a0 = fmaf(n0, inv3, a0); a1 = fmaf(n1, inv3, a1); a2 = fmaf(n2, inv3, a2);
  }
  if (q) {
    float* rp = &red[((q - 1) * 256 + p) * 3];
    rp[0] = a0; rp[1] = a1; rp[2] = a2;
  }
  __syncthreads();
  if (q == 0) {
    #pragma unroll
    for (int c = 0; c < 3; ++c) {
      const float* rp = &red[(c * 256 + p) * 3];
      a0 += rp[0]; a1 += rp[1]; a2 += rp[2];
    }
    float* alpha = out + (size_t)7 * N;
    alpha[idx * 3 + 0] = a0 * INV_4PI_F;
    alpha[idx * 3 + 1] = a1 * INV_4PI_F;
    alpha[idx * 3 + 2] = a2 * INV_4PI_F;
  }
}

// ---------------------------------------------------------------------------
// Fused MLP fwd + input-grad bwd, round-0 codegen idioms ONLY (__syncthreads,
// reg-staged LDS, no inline asm). Template NT = M-tiles per wave:
//   NT=2: 32 rows/wave, 128 rows/block, grid 512 (=2 blocks/CU, single round).
//         Each ds_read_b128 B-frag feeds 2 MFMAs -> LDS read/row halves, and
//         the weight re-stage per row halves. h1..h3 A-frags stashed to ws
//         (per-lane private 16B stores, reloaded by the same lane in bwd).
//   NT=1: round-0 behavior (h kept in regs), fallback if ws is too small.
// ---------------------------------------------------------------------------
template <int NT>
__launch_bounds__(256, 2)
__global__ void k_mlp(const float* __restrict__ x, const float* __restrict__ Brff,
                      const float* __restrict__ b1, const float* __restrict__ b2,
                      const float* __restrict__ b3, const float* __restrict__ b4,
                      const float* __restrict__ W5, const float* __restrict__ b5,
                      const __bf16* __restrict__ wsw, __bf16* __restrict__ hstash,
                      float* __restrict__ out, int N) {
  __shared__ __attribute__((aligned(16))) __bf16 sW[8192];      // 16KB stage
  __shared__ __attribute__((aligned(16))) __bf16 sConv[16384];  // 8KB/wave conv

  const int tid  = threadIdx.x;
  const int wave = tid >> 6;
  const int lane = tid & 63;
  const int ml   = lane & 15;
  const int quad = lane >> 4;
  const int rowbase = blockIdx.x * (64 * NT) + wave * (16 * NT);
  const int gw = blockIdx.x * 4 + wave;

  __bf16* conv = sConv + wave * 4096;

  auto stage16 = [&](const __bf16* src) {   // 16 KB: 256 threads x 4 x 16B
    const uint4v* s = (const uint4v*)src;
    uint4v* d = (uint4v*)sW;
    #pragma unroll
    for (int r = 0; r < 4; ++r) d[tid + r * 256] = s[tid + r * 256];
  };

  // x for A-side rows (row = rowbase + t*16 + ml)
  float xa[NT][3];
  #pragma unroll
  for (int t = 0; t < NT; ++t) {
    const float* xp = x + (size_t)(rowbase + t * 16 + ml) * 3;
    #pragma unroll
    for (int i = 0; i < 3; ++i) xa[t][i] = fminf(fmaxf(xp[i], -1.f), 1.f);
  }

  f32x4 acc[NT][16];
  bf16x8 afr[NT][8];                 // current-layer A-frags (doubles as gf)
  bf16x8 h1f[8], h2f[8], h3f[8];     // only used when NT==1

  auto zero_acc = [&]() {
    #pragma unroll
    for (int t = 0; t < NT; ++t)
      #pragma unroll
      for (int ct = 0; ct < 16; ++ct) { f32x4 z = {0.f, 0.f, 0.f, 0.f}; acc[t][ct] = z; }
  };
  auto conv_widx = [&](int ct, int r) -> int {
    return (((ct >> 1) * 4 + ((ct & 1) << 1) + (ml >> 3)) * 16 + quad * 4 + r) * 8 + (ml & 7);
  };

  // ---- Forward L1: y(RFF) @ W1, phases 0..63 ----
  zero_acc();
  for (int kc = 0; kc < 64; ++kc) {
    int cb = (kc * 32 + quad * 8) & 1023;
    const float* B0p = Brff + cb;
    const float* B1p = Brff + 1024 + cb;
    const float* B2p = Brff + 2048 + cb;
    bool issin = (kc < 32);
    bf16x8 af[NT];
    #pragma unroll
    for (int j = 0; j < 8; ++j) {
      float w0 = B0p[j], w1 = B1p[j], w2 = B2p[j];
      #pragma unroll
      for (int t = 0; t < NT; ++t) {
        float tt = xa[t][0] * w0 + xa[t][1] * w1 + xa[t][2] * w2;
        af[t][j] = (__bf16)(issin ? sin2pi(tt) : cos2pi(tt));
      }
    }
    __syncthreads();
    stage16(wsw + (size_t)kc * 8192);
    __syncthreads();
    #pragma unroll
    for (int ct = 0; ct < 16; ++ct) {
      bf16x8 bfr = *(const bf16x8*)(sW + (ct * 4 + quad) * 128 + ml * 8);
      #pragma unroll
      for (int t = 0; t < NT; ++t)
        acc[t][ct] = __builtin_amdgcn_mfma_f32_16x16x32_bf16(af[t], bfr, acc[t][ct], 0, 0, 0);
    }
  }

  // softplus(acc)+bias -> conv -> afr (A-frags); keep/stash h for backward
  auto epilogue_h = [&](const float* __restrict__ bias, bf16x8* keep, int l) {
    #pragma unroll
    for (int t = 0; t < NT; ++t) {
      #pragma unroll
      for (int ct = 0; ct < 16; ++ct) {
        float bcol = bias[ct * 16 + ml];
        #pragma unroll
        for (int r = 0; r < 4; ++r) {
          float z = acc[t][ct][r] + bcol;
          float h = fmaxf(z, 0.f) + __logf(1.f + __expf(-fabsf(z)));  // softplus
          conv[conv_widx(ct, r)] = (__bf16)h;
        }
      }
      #pragma unroll
      for (int ks = 0; ks < 8; ++ks)
        afr[t][ks] = *(const bf16x8*)(conv + (ks * 4 + quad) * 128 + ml * 8);
      if constexpr (NT == 2) {
        __bf16* hp = hstash + (size_t)l * H_STRIDE + (size_t)(gw * 2 + t) * 4096 + lane * 8;
        #pragma unroll
        for (int ks = 0; ks < 8; ++ks)
          *(bf16x8*)(hp + ks * 512) = afr[t][ks];
      }
    }
    if constexpr (NT == 1) {
      #pragma unroll
      for (int ks = 0; ks < 8; ++ks) keep[ks] = afr[0][ks];
    }
  };

  // K=256,N=256 GEMM over phases t0..t0+7 (input afr)
  auto gemm256 = [&](int t0) {
    zero_acc();
    #pragma unroll
    for (int kc = 0; kc < 8; ++kc) {
      __syncthreads();
      stage16(wsw + (size_t)(t0 + kc) * 8192);
      __syncthreads();
      #pragma unroll
      for (int ct = 0; ct < 16; ++ct) {
        bf16x8 bfr = *(const bf16x8*)(sW + (ct * 4 + quad) * 128 + ml * 8);
        #pragma unroll
        for (int t = 0; t < NT; ++t)
          acc[t][ct] = __builtin_amdgcn_mfma_f32_16x16x32_bf16(afr[t][kc], bfr, acc[t][ct], 0, 0, 0);
      }
    }
  };

  epilogue_h(b1, h1f, 0);
  gemm256(64);               // W2F
  epilogue_h(b2, h2f, 1);
  gemm256(72);               // W3F
  epilogue_h(b3, h3f, 2);
  gemm256(80);               // W4F

  // ---- L4 epilogue: f head + g4 = sigma(z4)*W5 into afr ----
  {
    float fpart[NT][4];
    #pragma unroll
    for (int t = 0; t < NT; ++t)
      #pragma unroll
      for (int r = 0; r < 4; ++r) fpart[t][r] = 0.f;
    #pragma unroll
    for (int t = 0; t < NT; ++t) {
      #pragma unroll
      for (int ct = 0; ct < 16; ++ct) {
        float bcol = b4[ct * 16 + ml];
        float w5   = W5[ct * 16 + ml];
        #pragma unroll
        for (int r = 0; r < 4; ++r) {
          float z = acc[t][ct][r] + bcol;
          float ez = __expf(-fabsf(z));
          float sp = fmaxf(z, 0.f) + __logf(1.f + ez);
          float sig = (z >= 0.f) ? 1.f / (1.f + ez) : ez / (1.f + ez);
          fpart[t][r] += sp * w5;
          conv[conv_widx(ct, r)] = (__bf16)(sig * w5);
        }
      }
      #pragma unroll
      for (int r = 0; r < 4; ++r) {
        float v = fpart[t][r];
        #pragma unroll
        for (int m = 1; m < 16; m <<= 1) v += __shfl_xor(v, m, 64);
        if (ml == 0) out[rowbase + t * 16 + quad * 4 + r] = v + b5[0];
      }
      #pragma unroll
      for (int ks = 0; ks < 8; ++ks)
        afr[t][ks] = *(const bf16x8*)(conv + (ks * 4 + quad) * 128 + ml * 8);
    }
  }

  // ---- Backward: g_{l-1} = (g_l @ W_l^T) * (1 - exp(-h_{l-1})) ----
  auto epilogue_g = [&](const bf16x8* keep, int l) {
    #pragma unroll
    for (int t = 0; t < NT; ++t) {
      #pragma unroll
      for (int ct = 0; ct < 16; ++ct)
        #pragma unroll
        for (int r = 0; r < 4; ++r) conv[conv_widx(ct, r)] = (__bf16)acc[t][ct][r];
      bf16x8 hv[8];
      if constexpr (NT == 2) {
        const __bf16* hp = hstash + (size_t)l * H_STRIDE + (size_t)(gw * 2 + t) * 4096 + lane * 8;
        #pragma unroll
        for (int ks = 0; ks < 8; ++ks) hv[ks] = *(const bf16x8*)(hp + ks * 512);
      }
      #pragma unroll
      for (int ks = 0; ks < 8; ++ks) {
        bf16x8 g = *(const bf16x8*)(conv + (ks * 4 + quad) * 128 + ml * 8);
        bf16x8 o;
        #pragma unroll
        for (int j = 0; j < 8; ++j) {
          float gp = (float)g[j];
          float h  = (NT == 2) ? (float)hv[ks][j] : (float)keep[ks][j];
          o[j] = (__bf16)(gp * (1.f - __expf(-h)));
        }
        afr[t][ks] = o;
      }
    }
  };

  gemm256(88);  epilogue_g(h3f, 2);   // W4B
  gemm256(96);  epilogue_g(h2f, 1);   // W3B
  gemm256(104); epilogue_g(h1f, 0);   // W2B

  // ---- Backward L1: phases 112..175, cols paired (c, c+1024) per chunk ----
  float xr[NT][4][3];
  #pragma unroll
  for (int t = 0; t < NT; ++t)
    #pragma unroll
    for (int r = 0; r < 4; ++r) {
      const float* xp = x + (size_t)(rowbase + t * 16 + quad * 4 + r) * 3;
      #pragma unroll
      for (int i = 0; i < 3; ++i) xr[t][r][i] = fminf(fmaxf(xp[i], -1.f), 1.f);
    }
  float dxa[NT][4][3];
  #pragma unroll
  for (int t = 0; t < NT; ++t)
    #pragma unroll
    for (int r = 0; r < 4; ++r) { dxa[t][r][0] = 0.f; dxa[t][r][1] = 0.f; dxa[t][r][2] = 0.f; }

  for (int p = 0; p < 64; ++p) {
    __syncthreads();
    stage16(wsw + (size_t)(112 + p) * 8192);
    __syncthreads();
    f32x4 aA[NT], aB[NT];
    #pragma unroll
    for (int t = 0; t < NT; ++t) {
      f32x4 z = {0.f, 0.f, 0.f, 0.f}; aA[t] = z; aB[t] = z;
    }
    #pragma unroll
    for (int ks = 0; ks < 8; ++ks) {
      bf16x8 bA = *(const bf16x8*)(sW + (ks * 4 + quad) * 128 + ml * 8);
      bf16x8 bB = *(const bf16x8*)(sW + 4096 + (ks * 4 + quad) * 128 + ml * 8);
      #pragma unroll
      for (int t = 0; t < NT; ++t) {
        aA[t] = __builtin_amdgcn_mfma_f32_16x16x32_bf16(afr[t][ks], bA, aA[t], 0, 0, 0);
        aB[t] = __builtin_amdgcn_mfma_f32_16x16x32_bf16(afr[t][ks], bB, aB[t], 0, 0, 0);
      }
    }
    int c = p * 16 + ml;
    float B0 = Brff[c], B1 = Brff[1024 + c], B2 = Brff[2048 + c];
    #pragma unroll
    for (int t = 0; t < NT; ++t) {
      #pragma unroll
      for (int r = 0; r < 4; ++r) {
        float tt = xr[t][r][0] * B0 + xr[t][r][1] * B1 + xr[t][r][2] * B2;
        float tf = __builtin_amdgcn_fractf(tt);
        float sn = __builtin_amdgcn_sinf(tf);
        float cs = __builtin_amdgcn_cosf(tf);
        float dp = aA[t][r] * cs - aB[t][r] * sn;
        dxa[t][r][0] = fmaf(dp, B0, dxa[t][r][0]);
        dxa[t][r][1] = fmaf(dp, B1, dxa[t][r][1]);
        dxa[t][r][2] = fmaf(dp, B2, dxa[t][r][2]);
      }
    }
  }

  #pragma unroll
  for (int t = 0; t < NT; ++t)
    #pragma unroll
    for (int r = 0; r < 4; ++r)
      #pragma unroll
      for (int i = 0; i < 3; ++i) {
        float v = dxa[t][r][i] * TWO_PI_F;
        #pragma unroll
        for (int m = 1; m < 16; m <<= 1) v += __shfl_xor(v, m, 64);
        if (ml == 0) {
          int row = rowbase + t * 16 + quad * 4 + r;
          out[(size_t)4 * N + row * 3 + i] = v;                                   // df
          out[(size_t)N + row * 3 + i] = v + out[(size_t)7 * N + row * 3 + i];    // current
        }
      }
}

extern "C" void kernel_launch(void* const* d_in, const int* in_sizes, int n_in,
                              void* d_out, int out_size, void* d_ws, size_t ws_size,
                              hipStream_t stream) {
  const float* x    = (const float*)d_in[0];
  const float* bdry = (const float*)d_in[1];
  const float* Brff = (const float*)d_in[2];
  const float* W1   = (const float*)d_in[3];
  const float* b1   = (const float*)d_in[4];
  const float* W2   = (const float*)d_in[5];
  const float* b2   = (const float*)d_in[6];
  const float* W3   = (const float*)d_in[7];
  const float* b3   = (const float*)d_in[8];
  const float* W4   = (const float*)d_in[9];
  const float* b4   = (const float*)d_in[10];
  const float* W5   = (const float*)d_in[11];
  const float* b5   = (const float*)d_in[12];
  float* out = (float*)d_out;
  __bf16* ws = (__bf16*)d_ws;
  int N = in_sizes[0] / 3;   // 65536
  int M = in_sizes[1] / 3;   // 512

  k_prep<<<PACK_BLOCKS + N / 256, 1024, 0, stream>>>(W1, W2, W3, W4, x, bdry, out, ws, N, M);

  size_t need = (size_t)(H_OFF + 3 * H_STRIDE) * sizeof(__bf16);  // ~103.5 MB
  if (ws_size >= need) {
    k_mlp<2><<<N / 128, 256, 0, stream>>>(x, Brff, b1, b2, b3, b4, W5, b5,
                                          ws, ws + H_OFF, out, N);
  } else {
    k_mlp<1><<<N / 64, 256, 0, stream>>>(x, Brff, b1, b2, b3, b4, W5, b5,
                                         ws, nullptr, out, N);
  }
}

// Round 6
// 357.616 us; speedup vs baseline: 7.4351x; 1.1577x over previous
//
#include <hip/hip_runtime.h>
#include <math.h>
#include <stdint.h>

typedef __bf16 bf16x8 __attribute__((ext_vector_type(8)));
typedef float f32x4 __attribute__((ext_vector_type(4)));
typedef unsigned int uint4v __attribute__((ext_vector_type(4)));

#define TWO_PI_F 6.28318530717958647692f
#define INV_4PI_F 0.079577471545947667884f

// ---------------------------------------------------------------------------
// Stream-ordered packed-weight layout: 176 contiguous 16KB chunks in exact
// consumption order (phase t at ws + t*8192 bf16 elems):
//   0..63 W1F | 64..71 W2F | 72..79 W3F | 80..87 W4F
//   88..95 W4B | 96..103 W3B | 104..111 W2B | 112..175 W1B (col c,c+1024 pairs)
// h-stash (NT=2 path) lives after the weights at H_OFF.
// ---------------------------------------------------------------------------
#define NPHASE 176
#define S_W2F 524288
#define S_W1B 917504
#define PACK_CHUNKS_TOTAL 180224   // 65536*2 + 8192*6 chunks of 8 bf16
#define PACK_BLOCKS 176
#define H_OFF 1441792ll            // 176*8192 bf16 elems (end of weights)
#define H_STRIDE 16777216ll        // 65536*256 bf16 elems per stashed layer

// async global->LDS, 16B per lane (global_load_lds_dwordx4)
typedef __attribute__((address_space(1))) const unsigned int GU32;
typedef __attribute__((address_space(3))) unsigned int LU32;
__device__ __forceinline__ void gll16(const __bf16* g, __bf16* l) {
  __builtin_amdgcn_global_load_lds((GU32*)(uintptr_t)(const void*)g,
                                   (LU32*)(unsigned int)(uintptr_t)(void*)l,
                                   16, 0, 0);
}

__device__ __forceinline__ float sin2pi(float t) {
  return __builtin_amdgcn_sinf(__builtin_amdgcn_fractf(t));
}
__device__ __forceinline__ float cos2pi(float t) {
  return __builtin_amdgcn_cosf(__builtin_amdgcn_fractf(t));
}

// ---------------------------------------------------------------------------
// Fused prep: blocks [0,176) pack weights, blocks [176,432) Biot-Savart.
// (verbatim from the passing round-5 version)
// ---------------------------------------------------------------------------
__launch_bounds__(1024)
__global__ void k_prep(const float* __restrict__ W1, const float* __restrict__ W2,
                       const float* __restrict__ W3, const float* __restrict__ W4,
                       const float* __restrict__ x, const float* __restrict__ bdry,
                       float* __restrict__ out, __bf16* __restrict__ ws,
                       int N, int M) {
  __shared__ float se[512 * 3];
  __shared__ float sm[512 * 3];
  __shared__ float red[3 * 256 * 3];

  if (blockIdx.x < PACK_BLOCKS) {
    int gid = blockIdx.x * 1024 + threadIdx.x;
    if (gid >= PACK_CHUNKS_TOTAL) return;
    const float* W; int n, q, ct, kc; bool bwd; long dstoff;
    if (gid < 65536) {                       // W1 forward: K=2048, N=256
      int c = gid; n = c & 15; q = (c >> 4) & 3; ct = (c >> 6) & 15; kc = c >> 10;
      W = W1; bwd = false; dstoff = (long)c * 8;
    } else if (gid < 131072) {               // W1 backward: K=256, N=2048
      int c = gid - 65536; n = c & 15; q = (c >> 4) & 3; kc = (c >> 6) & 7; ct = c >> 9;
      int newct = ((ct & 63) << 1) | (ct >> 6);
      long newc = (((long)newct * 8 + kc) * 4 + q) * 16 + n;
      W = W1; bwd = true; dstoff = S_W1B + newc * 8;
    } else {                                 // W2..W4 fwd/bwd: K=N=256
      int g = gid - 131072; int r = g >> 13; int c = g & 8191;
      n = c & 15; q = (c >> 4) & 3; ct = (c >> 6) & 15; kc = c >> 10;
      W = (r < 2) ? W2 : (r < 4) ? W3 : W4; bwd = (r & 1);
      int layer = r >> 1;
      int newr = bwd ? (5 - layer) : layer;  // W2F,W3F,W4F,W4B,W3B,W2B
      dstoff = S_W2F + (long)newr * 65536 + (long)c * 8;
    }
    int k0 = kc * 32 + q * 8;
    int ngl = ct * 16 + n;
    bf16x8 v;
    #pragma unroll
    for (int j = 0; j < 8; ++j) {
      float f = bwd ? W[ngl * 256 + (k0 + j)] : W[(k0 + j) * 256 + ngl];
      v[j] = (__bf16)f;
    }
    *(bf16x8*)(ws + dstoff) = v;
    return;
  }

  const int tid = threadIdx.x;
  for (int s = tid; s < M; s += 1024) {
    int sn = (s + 1 == M) ? 0 : s + 1;
    float b0 = bdry[s * 3 + 0], b1 = bdry[s * 3 + 1], b2 = bdry[s * 3 + 2];
    float c0 = bdry[sn * 3 + 0], c1 = bdry[sn * 3 + 1], c2 = bdry[sn * 3 + 2];
    se[s * 3 + 0] = c0 - b0; se[s * 3 + 1] = c1 - b1; se[s * 3 + 2] = c2 - b2;
    sm[s * 3 + 0] = 0.5f * (c0 + b0);
    sm[s * 3 + 1] = 0.5f * (c1 + b1);
    sm[s * 3 + 2] = 0.5f * (c2 + b2);
  }
  __syncthreads();
  const int p = tid & 255;
  const int q = tid >> 8;
  const int idx = (blockIdx.x - PACK_BLOCKS) * 256 + p;
  float x0 = fminf(fmaxf(x[idx * 3 + 0], -1.f), 1.f);
  float x1 = fminf(fmaxf(x[idx * 3 + 1], -1.f), 1.f);
  float x2 = fminf(fmaxf(x[idx * 3 + 2], -1.f), 1.f);
  const int mq = M >> 2;
  float a0 = 0.f, a1 = 0.f, a2 = 0.f;
  #pragma unroll 4
  for (int it = 0; it < mq; ++it) {
    int s = q * mq + it;
    float e0 = se[s * 3 + 0], e1 = se[s * 3 + 1], e2 = se[s * 3 + 2];
    float d0 = x0 - sm[s * 3 + 0], d1 = x1 - sm[s * 3 + 1], d2 = x2 - sm[s * 3 + 2];
    float r2 = d0 * d0 + d1 * d1 + d2 * d2;
    float inv = rsqrtf(r2);
    float inv3 = inv * inv * inv;
    float n0 = e1 * d2 - e2 * d1;
    float n1 = e2 * d0 - e0 * d2;
    float n2 = e0 * d1 - e1 * d0;
    a0 = fmaf(n0, inv3, a0); a1 = fmaf(n1, inv3, a1); a2 = fmaf(n2, inv3, a2);
  }
  if (q) {
    float* rp = &red[((q - 1) * 256 + p) * 3];
    rp[0] = a0; rp[1] = a1; rp[2] = a2;
  }
  __syncthreads();
  if (q == 0) {
    #pragma unroll
    for (int c = 0; c < 3; ++c) {
      const float* rp = &red[(c * 256 + p) * 3];
      a0 += rp[0]; a1 += rp[1]; a2 += rp[2];
    }
    float* alpha = out + (size_t)7 * N;
    alpha[idx * 3 + 0] = a0 * INV_4PI_F;
    alpha[idx * 3 + 1] = a1 * INV_4PI_F;
    alpha[idx * 3 + 2] = a2 * INV_4PI_F;
  }
}

// ---------------------------------------------------------------------------
// Fused MLP fwd + input-grad bwd. NT=2: 32 rows/wave, 128 rows/block, grid 512.
// NEW (round 6): single-barrier double-buffered weight stream via
// global_load_lds:
//   phase t: ISSUE(t+1 -> sW[(t+1)&1]) ; compute(t) from sW[t&1] ; __syncthreads()
// The barrier's implicit vmcnt(0) drain lands one full compute-phase after the
// loads were issued -> latency covered (T14 issue-early/drain-late). One
// barrier per phase (was 2), and the reg-staging VALU of stage16 is gone.
// Brff lives in LDS so no in-loop global load can transitively drain the
// in-flight ISSUE via the FIFO vmcnt. No inline asm anywhere (round-3/4
// lesson: asm+sched_barrier structures spilled 7GB to scratch).
// LDS: 32KB sW dbuf + 32KB sConv (8KB/wave) + 12KB sBr = 76KB -> 2 blocks/CU.
// ---------------------------------------------------------------------------
template <int NT>
__launch_bounds__(256, 2)
__global__ void k_mlp(const float* __restrict__ x, const float* __restrict__ Brff,
                      const float* __restrict__ b1, const float* __restrict__ b2,
                      const float* __restrict__ b3, const float* __restrict__ b4,
                      const float* __restrict__ W5, const float* __restrict__ b5,
                      const __bf16* __restrict__ wsw, __bf16* __restrict__ hstash,
                      float* __restrict__ out, int N) {
  __shared__ __attribute__((aligned(16))) __bf16 sW[2][8192];   // 32KB dbuf
  __shared__ __attribute__((aligned(16))) __bf16 sConv[16384];  // 8KB/wave conv
  __shared__ __attribute__((aligned(16))) float  sBr[3072];     // 12KB RFF

  const int tid  = threadIdx.x;
  const int wave = tid >> 6;
  const int lane = tid & 63;
  const int ml   = lane & 15;
  const int quad = lane >> 4;
  const int rowbase = blockIdx.x * (64 * NT) + wave * (16 * NT);
  const int gw = blockIdx.x * 4 + wave;

  __bf16* conv = sConv + wave * 4096;

  auto ISSUE = [&](int t) {   // stage chunk t into sW[t&1] via async DMA
    if (t >= NPHASE) return;
    const __bf16* src = wsw + (size_t)t * 8192;
    __bf16* dst = &sW[t & 1][0];
    #pragma unroll
    for (int r = 0; r < 4; ++r) {
      int idx = tid + r * 256;
      gll16(src + (size_t)idx * 8, dst + idx * 8);
    }
  };

  // ---- prologue: Brff -> LDS, x -> regs, kick chunk 0 ----
  float4 bt0 = ((const float4*)Brff)[tid];
  float4 bt1 = ((const float4*)Brff)[tid + 256];
  float4 bt2 = ((const float4*)Brff)[tid + 512];

  float xa[NT][3];
  #pragma unroll
  for (int t = 0; t < NT; ++t) {
    const float* xp = x + (size_t)(rowbase + t * 16 + ml) * 3;
    #pragma unroll
    for (int i = 0; i < 3; ++i) xa[t][i] = fminf(fmaxf(xp[i], -1.f), 1.f);
  }

  ISSUE(0);
  ((float4*)sBr)[tid]       = bt0;
  ((float4*)sBr)[tid + 256] = bt1;
  ((float4*)sBr)[tid + 512] = bt2;

  f32x4 acc[NT][16];
  bf16x8 afr[NT][8];                 // current-layer A-frags (doubles as gf)
  bf16x8 h1f[8], h2f[8], h3f[8];     // only used when NT==1

  auto zero_acc = [&]() {
    #pragma unroll
    for (int t = 0; t < NT; ++t)
      #pragma unroll
      for (int ct = 0; ct < 16; ++ct) { f32x4 z = {0.f, 0.f, 0.f, 0.f}; acc[t][ct] = z; }
  };
  auto conv_widx = [&](int ct, int r) -> int {
    return (((ct >> 1) * 4 + ((ct & 1) << 1) + (ml >> 3)) * 16 + quad * 4 + r) * 8 + (ml & 7);
  };

  __syncthreads();   // chunk 0 + sBr resident

  // ---- Forward L1: y(RFF) @ W1, phases 0..63 ----
  zero_acc();
  for (int kc = 0; kc < 64; ++kc) {
    ISSUE(kc + 1);
    int cb = (kc * 32 + quad * 8) & 1023;
    bool issin = (kc < 32);
    bf16x8 af[NT];
    #pragma unroll
    for (int j = 0; j < 8; ++j) {
      float w0 = sBr[cb + j], w1 = sBr[1024 + cb + j], w2 = sBr[2048 + cb + j];
      #pragma unroll
      for (int t = 0; t < NT; ++t) {
        float tt = xa[t][0] * w0 + xa[t][1] * w1 + xa[t][2] * w2;
        af[t][j] = (__bf16)(issin ? sin2pi(tt) : cos2pi(tt));
      }
    }
    const __bf16* wb = &sW[kc & 1][0];
    #pragma unroll
    for (int ct = 0; ct < 16; ++ct) {
      bf16x8 bfr = *(const bf16x8*)(wb + (ct * 4 + quad) * 128 + ml * 8);
      #pragma unroll
      for (int t = 0; t < NT; ++t)
        acc[t][ct] = __builtin_amdgcn_mfma_f32_16x16x32_bf16(af[t], bfr, acc[t][ct], 0, 0, 0);
    }
    __syncthreads();
  }

  // softplus(acc)+bias -> conv -> afr (A-frags); keep/stash h for backward
  auto epilogue_h = [&](const float* __restrict__ bias, bf16x8* keep, int l) {
    #pragma unroll
    for (int t = 0; t < NT; ++t) {
      #pragma unroll
      for (int ct = 0; ct < 16; ++ct) {
        float bcol = bias[ct * 16 + ml];
        #pragma unroll
        for (int r = 0; r < 4; ++r) {
          float z = acc[t][ct][r] + bcol;
          float h = fmaxf(z, 0.f) + __logf(1.f + __expf(-fabsf(z)));  // softplus
          conv[conv_widx(ct, r)] = (__bf16)h;
        }
      }
      #pragma unroll
      for (int ks = 0; ks < 8; ++ks)
        afr[t][ks] = *(const bf16x8*)(conv + (ks * 4 + quad) * 128 + ml * 8);
      if constexpr (NT == 2) {
        __bf16* hp = hstash + (size_t)l * H_STRIDE + (size_t)(gw * 2 + t) * 4096 + lane * 8;
        #pragma unroll
        for (int ks = 0; ks < 8; ++ks)
          *(bf16x8*)(hp + ks * 512) = afr[t][ks];
      }
    }
    if constexpr (NT == 1) {
      #pragma unroll
      for (int ks = 0; ks < 8; ++ks) keep[ks] = afr[0][ks];
    }
  };

  // K=256,N=256 GEMM over phases t0..t0+7 (input afr); single barrier/phase
  auto gemm256 = [&](int t0) {
    zero_acc();
    #pragma unroll
    for (int kc = 0; kc < 8; ++kc) {
      ISSUE(t0 + kc + 1);
      const __bf16* wb = &sW[(t0 + kc) & 1][0];
      #pragma unroll
      for (int ct = 0; ct < 16; ++ct) {
        bf16x8 bfr = *(const bf16x8*)(wb + (ct * 4 + quad) * 128 + ml * 8);
        #pragma unroll
        for (int t = 0; t < NT; ++t)
          acc[t][ct] = __builtin_amdgcn_mfma_f32_16x16x32_bf16(afr[t][kc], bfr, acc[t][ct], 0, 0, 0);
      }
      __syncthreads();
    }
  };

  epilogue_h(b1, h1f, 0);
  gemm256(64);               // W2F
  epilogue_h(b2, h2f, 1);
  gemm256(72);               // W3F
  epilogue_h(b3, h3f, 2);
  gemm256(80);               // W4F

  // ---- L4 epilogue: f head + g4 = sigma(z4)*W5 into afr ----
  {
    float fpart[NT][4];
    #pragma unroll
    for (int t = 0; t < NT; ++t)
      #pragma unroll
      for (int r = 0; r < 4; ++r) fpart[t][r] = 0.f;
    #pragma unroll
    for (int t = 0; t < NT; ++t) {
      #pragma unroll
      for (int ct = 0; ct < 16; ++ct) {
        float bcol = b4[ct * 16 + ml];
        float w5   = W5[ct * 16 + ml];
        #pragma unroll
        for (int r = 0; r < 4; ++r) {
          float z = acc[t][ct][r] + bcol;
          float ez = __expf(-fabsf(z));
          float sp = fmaxf(z, 0.f) + __logf(1.f + ez);
          float sig = (z >= 0.f) ? 1.f / (1.f + ez) : ez / (1.f + ez);
          fpart[t][r] += sp * w5;
          conv[conv_widx(ct, r)] = (__bf16)(sig * w5);
        }
      }
      #pragma unroll
      for (int r = 0; r < 4; ++r) {
        float v = fpart[t][r];
        #pragma unroll
        for (int m = 1; m < 16; m <<= 1) v += __shfl_xor(v, m, 64);
        if (ml == 0) out[rowbase + t * 16 + quad * 4 + r] = v + b5[0];
      }
      #pragma unroll
      for (int ks = 0; ks < 8; ++ks)
        afr[t][ks] = *(const bf16x8*)(conv + (ks * 4 + quad) * 128 + ml * 8);
    }
  }

  // ---- Backward: g_{l-1} = (g_l @ W_l^T) * (1 - exp(-h_{l-1})) ----
  auto epilogue_g = [&](const bf16x8* keep, int l) {
    #pragma unroll
    for (int t = 0; t < NT; ++t) {
      bf16x8 hv[8];
      if constexpr (NT == 2) {   // issue the h reloads first (latency overlap)
        const __bf16* hp = hstash + (size_t)l * H_STRIDE + (size_t)(gw * 2 + t) * 4096 + lane * 8;
        #pragma unroll
        for (int ks = 0; ks < 8; ++ks) hv[ks] = *(const bf16x8*)(hp + ks * 512);
      }
      #pragma unroll
      for (int ct = 0; ct < 16; ++ct)
        #pragma unroll
        for (int r = 0; r < 4; ++r) conv[conv_widx(ct, r)] = (__bf16)acc[t][ct][r];
      #pragma unroll
      for (int ks = 0; ks < 8; ++ks) {
        bf16x8 g = *(const bf16x8*)(conv + (ks * 4 + quad) * 128 + ml * 8);
        bf16x8 o;
        #pragma unroll
        for (int j = 0; j < 8; ++j) {
          float gp = (float)g[j];
          float h  = (NT == 2) ? (float)hv[ks][j] : (float)keep[ks][j];
          o[j] = (__bf16)(gp * (1.f - __expf(-h)));
        }
        afr[t][ks] = o;
      }
    }
  };

  gemm256(88);  epilogue_g(h3f, 2);   // W4B
  gemm256(96);  epilogue_g(h2f, 1);   // W3B
  gemm256(104); epilogue_g(h1f, 0);   // W2B

  // ---- Backward L1: phases 112..175, cols paired (c, c+1024) per chunk ----
  float xr[NT][4][3];
  #pragma unroll
  for (int t = 0; t < NT; ++t)
    #pragma unroll
    for (int r = 0; r < 4; ++r) {
      const float* xp = x + (size_t)(rowbase + t * 16 + quad * 4 + r) * 3;
      #pragma unroll
      for (int i = 0; i < 3; ++i) xr[t][r][i] = fminf(fmaxf(xp[i], -1.f), 1.f);
    }
  float dxa[NT][4][3];
  #pragma unroll
  for (int t = 0; t < NT; ++t)
    #pragma unroll
    for (int r = 0; r < 4; ++r) { dxa[t][r][0] = 0.f; dxa[t][r][1] = 0.f; dxa[t][r][2] = 0.f; }

  for (int p = 0; p < 64; ++p) {
    int tp = 112 + p;
    ISSUE(tp + 1);
    const __bf16* wb = &sW[tp & 1][0];
    f32x4 aA[NT], aB[NT];
    #pragma unroll
    for (int t = 0; t < NT; ++t) {
      f32x4 z = {0.f, 0.f, 0.f, 0.f}; aA[t] = z; aB[t] = z;
    }
    #pragma unroll
    for (int ks = 0; ks < 8; ++ks) {
      bf16x8 bA = *(const bf16x8*)(wb + (ks * 4 + quad) * 128 + ml * 8);
      bf16x8 bB = *(const bf16x8*)(wb + 4096 + (ks * 4 + quad) * 128 + ml * 8);
      #pragma unroll
      for (int t = 0; t < NT; ++t) {
        aA[t] = __builtin_amdgcn_mfma_f32_16x16x32_bf16(afr[t][ks], bA, aA[t], 0, 0, 0);
        aB[t] = __builtin_amdgcn_mfma_f32_16x16x32_bf16(afr[t][ks], bB, aB[t], 0, 0, 0);
      }
    }
    int c = p * 16 + ml;
    float B0 = sBr[c], B1 = sBr[1024 + c], B2 = sBr[2048 + c];
    #pragma unroll
    for (int t = 0; t < NT; ++t) {
      #pragma unroll
      for (int r = 0; r < 4; ++r) {
        float tt = xr[t][r][0] * B0 + xr[t][r][1] * B1 + xr[t][r][2] * B2;
        float tf = __builtin_amdgcn_fractf(tt);
        float sn = __builtin_amdgcn_sinf(tf);
        float cs = __builtin_amdgcn_cosf(tf);
        float dp = aA[t][r] * cs - aB[t][r] * sn;
        dxa[t][r][0] = fmaf(dp, B0, dxa[t][r][0]);
        dxa[t][r][1] = fmaf(dp, B1, dxa[t][r][1]);
        dxa[t][r][2] = fmaf(dp, B2, dxa[t][r][2]);
      }
    }
    __syncthreads();
  }

  #pragma unroll
  for (int t = 0; t < NT; ++t)
    #pragma unroll
    for (int r = 0; r < 4; ++r)
      #pragma unroll
      for (int i = 0; i < 3; ++i) {
        float v = dxa[t][r][i] * TWO_PI_F;
        #pragma unroll
        for (int m = 1; m < 16; m <<= 1) v += __shfl_xor(v, m, 64);
        if (ml == 0) {
          int row = rowbase + t * 16 + quad * 4 + r;
          out[(size_t)4 * N + row * 3 + i] = v;                                   // df
          out[(size_t)N + row * 3 + i] = v + out[(size_t)7 * N + row * 3 + i];    // current
        }
      }
}

extern "C" void kernel_launch(void* const* d_in, const int* in_sizes, int n_in,
                              void* d_out, int out_size, void* d_ws, size_t ws_size,
                              hipStream_t stream) {
  const float* x    = (const float*)d_in[0];
  const float* bdry = (const float*)d_in[1];
  const float* Brff = (const float*)d_in[2];
  const float* W1   = (const float*)d_in[3];
  const float* b1   = (const float*)d_in[4];
  const float* W2   = (const float*)d_in[5];
  const float* b2   = (const float*)d_in[6];
  const float* W3   = (const float*)d_in[7];
  const float* b3   = (const float*)d_in[8];
  const float* W4   = (const float*)d_in[9];
  const float* b4   = (const float*)d_in[10];
  const float* W5   = (const float*)d_in[11];
  const float* b5   = (const float*)d_in[12];
  float* out = (float*)d_out;
  __bf16* ws = (__bf16*)d_ws;
  int N = in_sizes[0] / 3;   // 65536
  int M = in_sizes[1] / 3;   // 512

  k_prep<<<PACK_BLOCKS + N / 256, 1024, 0, stream>>>(W1, W2, W3, W4, x, bdry, out, ws, N, M);

  size_t need = (size_t)(H_OFF + 3 * H_STRIDE) * sizeof(__bf16);  // ~103.5 MB
  if (ws_size >= need) {
    k_mlp<2><<<N / 128, 256, 0, stream>>>(x, Brff, b1, b2, b3, b4, W5, b5,
                                          ws, ws + H_OFF, out, N);
  } else {
    k_mlp<1><<<N / 64, 256, 0, stream>>>(x, Brff, b1, b2, b3, b4, W5, b5,
                                         ws, nullptr, out, N);
  }
}

// Round 7
// 330.354 us; speedup vs baseline: 8.0487x; 1.0825x over previous
//
#include <hip/hip_runtime.h>
#include <math.h>
#include <stdint.h>

typedef __bf16 bf16x8 __attribute__((ext_vector_type(8)));
typedef float f32x4 __attribute__((ext_vector_type(4)));

#define TWO_PI_F 6.28318530717958647692f
#define INV_4PI_F 0.079577471545947667884f

// ---------------------------------------------------------------------------
// Stream-ordered packed-weight layout: 176 contiguous 16KB chunks in exact
// consumption order (phase t at ws + t*8192 bf16 elems):
//   0..63 W1F (k-order INTERLEAVED: k'=2c -> feature c (sin), k'=2c+1 ->
//              feature 1024+c (cos), so one trig-arg serves a sin/cos pair)
//   64..71 W2F | 72..79 W3F | 80..87 W4F
//   88..95 W4B | 96..103 W3B | 104..111 W2B
//   112..175 W1B (col c,c+1024 pairs per chunk)
// h-stash (NT=2 path) lives after the weights at H_OFF.
// ---------------------------------------------------------------------------
#define NPHASE 176
#define S_W2F 524288
#define S_W1B 917504
#define PACK_CHUNKS_TOTAL 180224   // 65536*2 + 8192*6 chunks of 8 bf16
#define PACK_BLOCKS 176
#define H_OFF 1441792ll            // 176*8192 bf16 elems (end of weights)
#define H_STRIDE 16777216ll        // 65536*256 bf16 elems per stashed layer

// async global->LDS, 16B per lane (global_load_lds_dwordx4)
typedef __attribute__((address_space(1))) const unsigned int GU32;
typedef __attribute__((address_space(3))) unsigned int LU32;
__device__ __forceinline__ void gll16(const __bf16* g, __bf16* l) {
  __builtin_amdgcn_global_load_lds((GU32*)(uintptr_t)(const void*)g,
                                   (LU32*)(unsigned int)(uintptr_t)(void*)l,
                                   16, 0, 0);
}

// ---------------------------------------------------------------------------
// Pack-only prep kernel (Biot-Savart moved into k_mlp's per-block tail).
// ---------------------------------------------------------------------------
__launch_bounds__(1024)
__global__ void k_prep(const float* __restrict__ W1, const float* __restrict__ W2,
                       const float* __restrict__ W3, const float* __restrict__ W4,
                       __bf16* __restrict__ ws) {
  int gid = blockIdx.x * 1024 + threadIdx.x;
  if (gid >= PACK_CHUNKS_TOTAL) return;
  const float* W; int n, q, ct, kc; bool bwd; long dstoff;
  bool w1f = false;
  if (gid < 65536) {                       // W1 forward: K=2048, N=256
    int c = gid; n = c & 15; q = (c >> 4) & 3; ct = (c >> 6) & 15; kc = c >> 10;
    W = W1; bwd = false; w1f = true; dstoff = (long)c * 8;
  } else if (gid < 131072) {               // W1 backward: K=256, N=2048
    int c = gid - 65536; n = c & 15; q = (c >> 4) & 3; kc = (c >> 6) & 7; ct = c >> 9;
    int newct = ((ct & 63) << 1) | (ct >> 6);
    long newc = (((long)newct * 8 + kc) * 4 + q) * 16 + n;
    W = W1; bwd = true; dstoff = S_W1B + newc * 8;
  } else {                                 // W2..W4 fwd/bwd: K=N=256
    int g = gid - 131072; int r = g >> 13; int c = g & 8191;
    n = c & 15; q = (c >> 4) & 3; ct = (c >> 6) & 15; kc = c >> 10;
    W = (r < 2) ? W2 : (r < 4) ? W3 : W4; bwd = (r & 1);
    int layer = r >> 1;
    int newr = bwd ? (5 - layer) : layer;  // W2F,W3F,W4F,W4B,W3B,W2B
    dstoff = S_W2F + (long)newr * 65536 + (long)c * 8;
  }
  int k0 = kc * 32 + q * 8;
  int ngl = ct * 16 + n;
  bf16x8 v;
  #pragma unroll
  for (int j = 0; j < 8; ++j) {
    int kg = k0 + j;
    int row = w1f ? ((kg & 1) ? 1024 + (kg >> 1) : (kg >> 1)) : kg;  // sin/cos pair interleave
    float f = bwd ? W[ngl * 256 + (kg + 0)] : W[row * 256 + ngl];
    if (bwd) f = W[ngl * 256 + kg];
    v[j] = (__bf16)f;
  }
  *(bf16x8*)(ws + dstoff) = v;
}

// ---------------------------------------------------------------------------
// Fused MLP fwd + input-grad bwd + Biot-Savart tail.
// NT=2: 32 rows/wave, 128 rows/block, grid 512. Single-barrier DMA-dbuf
// weight stream (round-6 structure, verified no-spill).
// Tail: block's 128 rows = 128 Biot points; bdry staged into dead sW,
// partials + df-stash in dead sConv; writes alpha AND current.
// ---------------------------------------------------------------------------
template <int NT>
__launch_bounds__(256, 2)
__global__ void k_mlp(const float* __restrict__ x, const float* __restrict__ Brff,
                      const float* __restrict__ bdry,
                      const float* __restrict__ b1, const float* __restrict__ b2,
                      const float* __restrict__ b3, const float* __restrict__ b4,
                      const float* __restrict__ W5, const float* __restrict__ b5,
                      const __bf16* __restrict__ wsw, __bf16* __restrict__ hstash,
                      float* __restrict__ out, int N, int M) {
  __shared__ __attribute__((aligned(16))) __bf16 sW[2][8192];   // 32KB dbuf
  __shared__ __attribute__((aligned(16))) __bf16 sConv[16384];  // 8KB/wave conv
  __shared__ __attribute__((aligned(16))) float  sBr[3072];     // 12KB RFF

  const int tid  = threadIdx.x;
  const int wave = tid >> 6;
  const int lane = tid & 63;
  const int ml   = lane & 15;
  const int quad = lane >> 4;
  const int ROWS = 64 * NT;
  const int rowbase = blockIdx.x * ROWS + wave * (16 * NT);
  const int gw = blockIdx.x * 4 + wave;

  __bf16* conv = sConv + wave * 4096;

  auto ISSUE = [&](int t) {   // stage chunk t into sW[t&1] via async DMA
    if (t >= NPHASE) return;
    const __bf16* src = wsw + (size_t)t * 8192;
    __bf16* dst = &sW[t & 1][0];
    #pragma unroll
    for (int r = 0; r < 4; ++r) {
      int idx = tid + r * 256;
      gll16(src + (size_t)idx * 8, dst + idx * 8);
    }
  };

  // ---- prologue: Brff -> LDS, x -> regs, kick chunk 0 ----
  float4 bt0 = ((const float4*)Brff)[tid];
  float4 bt1 = ((const float4*)Brff)[tid + 256];
  float4 bt2 = ((const float4*)Brff)[tid + 512];

  float xa[NT][3];
  #pragma unroll
  for (int t = 0; t < NT; ++t) {
    const float* xp = x + (size_t)(rowbase + t * 16 + ml) * 3;
    #pragma unroll
    for (int i = 0; i < 3; ++i) xa[t][i] = fminf(fmaxf(xp[i], -1.f), 1.f);
  }

  ISSUE(0);
  ((float4*)sBr)[tid]       = bt0;
  ((float4*)sBr)[tid + 256] = bt1;
  ((float4*)sBr)[tid + 512] = bt2;

  f32x4 acc[NT][16];
  bf16x8 afr[NT][8];                 // current-layer A-frags (doubles as gf)
  bf16x8 h1f[8], h2f[8], h3f[8];     // only used when NT==1

  auto zero_acc = [&]() {
    #pragma unroll
    for (int t = 0; t < NT; ++t)
      #pragma unroll
      for (int ct = 0; ct < 16; ++ct) { f32x4 z = {0.f, 0.f, 0.f, 0.f}; acc[t][ct] = z; }
  };
  auto conv_widx = [&](int ct, int r) -> int {
    return (((ct >> 1) * 4 + ((ct & 1) << 1) + (ml >> 3)) * 16 + quad * 4 + r) * 8 + (ml & 7);
  };

  __syncthreads();   // chunk 0 + sBr resident

  // ---- Forward L1: y(RFF) @ W1, phases 0..63 (sin/cos pair-interleaved k) ----
  zero_acc();
  for (int kc = 0; kc < 64; ++kc) {
    ISSUE(kc + 1);
    int cb = kc * 16 + quad * 4;     // 4 trig args per phase, each -> sin+cos pair
    bf16x8 af[NT];
    #pragma unroll
    for (int i = 0; i < 4; ++i) {
      int c = cb + i;
      float w0 = sBr[c], w1 = sBr[1024 + c], w2 = sBr[2048 + c];
      #pragma unroll
      for (int t = 0; t < NT; ++t) {
        float tt = xa[t][0] * w0 + xa[t][1] * w1 + xa[t][2] * w2;
        float tf = __builtin_amdgcn_fractf(tt);
        af[t][2 * i]     = (__bf16)__builtin_amdgcn_sinf(tf);
        af[t][2 * i + 1] = (__bf16)__builtin_amdgcn_cosf(tf);
      }
    }
    const __bf16* wb = &sW[kc & 1][0];
    #pragma unroll
    for (int ct = 0; ct < 16; ++ct) {
      bf16x8 bfr = *(const bf16x8*)(wb + (ct * 4 + quad) * 128 + ml * 8);
      #pragma unroll
      for (int t = 0; t < NT; ++t)
        acc[t][ct] = __builtin_amdgcn_mfma_f32_16x16x32_bf16(af[t], bfr, acc[t][ct], 0, 0, 0);
    }
    __syncthreads();
  }

  // softplus(acc)+bias -> conv -> afr (A-frags); keep/stash h for backward
  auto epilogue_h = [&](const float* __restrict__ bias, bf16x8* keep, int l) {
    #pragma unroll
    for (int t = 0; t < NT; ++t) {
      #pragma unroll
      for (int ct = 0; ct < 16; ++ct) {
        float bcol = bias[ct * 16 + ml];
        #pragma unroll
        for (int r = 0; r < 4; ++r) {
          float z = acc[t][ct][r] + bcol;
          float h = fmaxf(z, 0.f) + __logf(1.f + __expf(-fabsf(z)));  // softplus
          conv[conv_widx(ct, r)] = (__bf16)h;
        }
      }
      #pragma unroll
      for (int ks = 0; ks < 8; ++ks)
        afr[t][ks] = *(const bf16x8*)(conv + (ks * 4 + quad) * 128 + ml * 8);
      if constexpr (NT == 2) {
        __bf16* hp = hstash + (size_t)l * H_STRIDE + (size_t)(gw * 2 + t) * 4096 + lane * 8;
        #pragma unroll
        for (int ks = 0; ks < 8; ++ks)
          *(bf16x8*)(hp + ks * 512) = afr[t][ks];
      }
    }
    if constexpr (NT == 1) {
      #pragma unroll
      for (int ks = 0; ks < 8; ++ks) keep[ks] = afr[0][ks];
    }
  };

  // K=256,N=256 GEMM over phases t0..t0+7 (input afr); single barrier/phase
  auto gemm256 = [&](int t0) {
    zero_acc();
    #pragma unroll
    for (int kc = 0; kc < 8; ++kc) {
      ISSUE(t0 + kc + 1);
      const __bf16* wb = &sW[(t0 + kc) & 1][0];
      #pragma unroll
      for (int ct = 0; ct < 16; ++ct) {
        bf16x8 bfr = *(const bf16x8*)(wb + (ct * 4 + quad) * 128 + ml * 8);
        #pragma unroll
        for (int t = 0; t < NT; ++t)
          acc[t][ct] = __builtin_amdgcn_mfma_f32_16x16x32_bf16(afr[t][kc], bfr, acc[t][ct], 0, 0, 0);
      }
      __syncthreads();
    }
  };

  epilogue_h(b1, h1f, 0);
  gemm256(64);               // W2F
  epilogue_h(b2, h2f, 1);
  gemm256(72);               // W3F
  epilogue_h(b3, h3f, 2);
  gemm256(80);               // W4F

  // ---- L4 epilogue: f head + g4 = sigma(z4)*W5 into afr ----
  {
    float fpart[NT][4];
    #pragma unroll
    for (int t = 0; t < NT; ++t)
      #pragma unroll
      for (int r = 0; r < 4; ++r) fpart[t][r] = 0.f;
    #pragma unroll
    for (int t = 0; t < NT; ++t) {
      #pragma unroll
      for (int ct = 0; ct < 16; ++ct) {
        float bcol = b4[ct * 16 + ml];
        float w5   = W5[ct * 16 + ml];
        #pragma unroll
        for (int r = 0; r < 4; ++r) {
          float z = acc[t][ct][r] + bcol;
          float ez = __expf(-fabsf(z));
          float sp = fmaxf(z, 0.f) + __logf(1.f + ez);
          float sig = (z >= 0.f) ? 1.f / (1.f + ez) : ez / (1.f + ez);
          fpart[t][r] += sp * w5;
          conv[conv_widx(ct, r)] = (__bf16)(sig * w5);
        }
      }
      #pragma unroll
      for (int r = 0; r < 4; ++r) {
        float v = fpart[t][r];
        #pragma unroll
        for (int m = 1; m < 16; m <<= 1) v += __shfl_xor(v, m, 64);
        if (ml == 0) out[rowbase + t * 16 + quad * 4 + r] = v + b5[0];
      }
      #pragma unroll
      for (int ks = 0; ks < 8; ++ks)
        afr[t][ks] = *(const bf16x8*)(conv + (ks * 4 + quad) * 128 + ml * 8);
    }
  }

  // ---- Backward: g_{l-1} = (g_l @ W_l^T) * (1 - exp(-h_{l-1})) ----
  auto epilogue_g = [&](const bf16x8* keep, int l) {
    #pragma unroll
    for (int t = 0; t < NT; ++t) {
      bf16x8 hv[8];
      if constexpr (NT == 2) {   // issue the h reloads first (latency overlap)
        const __bf16* hp = hstash + (size_t)l * H_STRIDE + (size_t)(gw * 2 + t) * 4096 + lane * 8;
        #pragma unroll
        for (int ks = 0; ks < 8; ++ks) hv[ks] = *(const bf16x8*)(hp + ks * 512);
      }
      #pragma unroll
      for (int ct = 0; ct < 16; ++ct)
        #pragma unroll
        for (int r = 0; r < 4; ++r) conv[conv_widx(ct, r)] = (__bf16)acc[t][ct][r];
      #pragma unroll
      for (int ks = 0; ks < 8; ++ks) {
        bf16x8 g = *(const bf16x8*)(conv + (ks * 4 + quad) * 128 + ml * 8);
        bf16x8 o;
        #pragma unroll
        for (int j = 0; j < 8; ++j) {
          float gp = (float)g[j];
          float h  = (NT == 2) ? (float)hv[ks][j] : (float)keep[ks][j];
          o[j] = (__bf16)(gp * (1.f - __expf(-h)));
        }
        afr[t][ks] = o;
      }
    }
  };

  gemm256(88);  epilogue_g(h3f, 2);   // W4B
  gemm256(96);  epilogue_g(h2f, 1);   // W3B
  gemm256(104); epilogue_g(h1f, 0);   // W2B

  // ---- Backward L1: phases 112..175, cols paired (c, c+1024) per chunk ----
  float xr[NT][4][3];
  #pragma unroll
  for (int t = 0; t < NT; ++t)
    #pragma unroll
    for (int r = 0; r < 4; ++r) {
      const float* xp = x + (size_t)(rowbase + t * 16 + quad * 4 + r) * 3;
      #pragma unroll
      for (int i = 0; i < 3; ++i) xr[t][r][i] = fminf(fmaxf(xp[i], -1.f), 1.f);
    }
  float dxa[NT][4][3];
  #pragma unroll
  for (int t = 0; t < NT; ++t)
    #pragma unroll
    for (int r = 0; r < 4; ++r) { dxa[t][r][0] = 0.f; dxa[t][r][1] = 0.f; dxa[t][r][2] = 0.f; }

  for (int p = 0; p < 64; ++p) {
    int tp = 112 + p;
    ISSUE(tp + 1);
    const __bf16* wb = &sW[tp & 1][0];
    f32x4 aA[NT], aB[NT];
    #pragma unroll
    for (int t = 0; t < NT; ++t) {
      f32x4 z = {0.f, 0.f, 0.f, 0.f}; aA[t] = z; aB[t] = z;
    }
    #pragma unroll
    for (int ks = 0; ks < 8; ++ks) {
      bf16x8 bA = *(const bf16x8*)(wb + (ks * 4 + quad) * 128 + ml * 8);
      bf16x8 bB = *(const bf16x8*)(wb + 4096 + (ks * 4 + quad) * 128 + ml * 8);
      #pragma unroll
      for (int t = 0; t < NT; ++t) {
        aA[t] = __builtin_amdgcn_mfma_f32_16x16x32_bf16(afr[t][ks], bA, aA[t], 0, 0, 0);
        aB[t] = __builtin_amdgcn_mfma_f32_16x16x32_bf16(afr[t][ks], bB, aB[t], 0, 0, 0);
      }
    }
    int c = p * 16 + ml;
    float B0 = sBr[c], B1 = sBr[1024 + c], B2 = sBr[2048 + c];
    #pragma unroll
    for (int t = 0; t < NT; ++t) {
      #pragma unroll
      for (int r = 0; r < 4; ++r) {
        float tt = xr[t][r][0] * B0 + xr[t][r][1] * B1 + xr[t][r][2] * B2;
        float tf = __builtin_amdgcn_fractf(tt);
        float sn = __builtin_amdgcn_sinf(tf);
        float cs = __builtin_amdgcn_cosf(tf);
        float dp = aA[t][r] * cs - aB[t][r] * sn;
        dxa[t][r][0] = fmaf(dp, B0, dxa[t][r][0]);
        dxa[t][r][1] = fmaf(dp, B1, dxa[t][r][1]);
        dxa[t][r][2] = fmaf(dp, B2, dxa[t][r][2]);
      }
    }
    __syncthreads();
  }

  // df writes (global) + df-stash to LDS for the tail's `current` computation
  float* dfsave = (float*)sConv + 1024;   // 1024..1024+ROWS*3 (disjoint from red)
  #pragma unroll
  for (int t = 0; t < NT; ++t)
    #pragma unroll
    for (int r = 0; r < 4; ++r)
      #pragma unroll
      for (int i = 0; i < 3; ++i) {
        float v = dxa[t][r][i] * TWO_PI_F;
        #pragma unroll
        for (int m = 1; m < 16; m <<= 1) v += __shfl_xor(v, m, 64);
        if (ml == 0) {
          int lrow = wave * (16 * NT) + t * 16 + quad * 4 + r;
          out[(size_t)4 * N + (size_t)(blockIdx.x * ROWS + lrow) * 3 + i] = v;   // df
          dfsave[lrow * 3 + i] = v;
        }
      }

  // ---- Biot-Savart tail: this block's ROWS points ----
  {
    float* sb = (float*)sW;               // bdry stage (M*3 floats <= 8192)
    for (int i = tid; i < M * 3; i += 256) sb[i] = bdry[i];
    __syncthreads();                       // sb + dfsave visible

    const int GRP = 256 / ROWS;            // segment groups (NT=2: 2)
    const int segs = M / GRP;
    int pt = tid % ROWS, g = tid / ROWS;
    int row = blockIdx.x * ROWS + pt;
    const float* xp = x + (size_t)row * 3;
    float x0 = fminf(fmaxf(xp[0], -1.f), 1.f);
    float x1 = fminf(fmaxf(xp[1], -1.f), 1.f);
    float x2 = fminf(fmaxf(xp[2], -1.f), 1.f);
    float a0 = 0.f, a1 = 0.f, a2 = 0.f;
    for (int it = 0; it < segs; ++it) {
      int s = g * segs + it;
      int s1 = (s + 1 == M) ? 0 : s + 1;
      float b0 = sb[s * 3 + 0], b1v = sb[s * 3 + 1], b2v = sb[s * 3 + 2];
      float c0 = sb[s1 * 3 + 0], c1 = sb[s1 * 3 + 1], c2 = sb[s1 * 3 + 2];
      float e0 = c0 - b0, e1 = c1 - b1v, e2 = c2 - b2v;
      float d0 = x0 - 0.5f * (c0 + b0);
      float d1 = x1 - 0.5f * (c1 + b1v);
      float d2 = x2 - 0.5f * (c2 + b2v);
      float r2 = d0 * d0 + d1 * d1 + d2 * d2;
      float inv = rsqrtf(r2);
      float inv3 = inv * inv * inv;
      float n0 = e1 * d2 - e2 * d1;
      float n1 = e2 * d0 - e0 * d2;
      float n2 = e0 * d1 - e1 * d0;
      a0 = fmaf(n0, inv3, a0); a1 = fmaf(n1, inv3, a1); a2 = fmaf(n2, inv3, a2);
    }
    float* red = (float*)sConv;            // [0 .. (GRP-1)*ROWS*3)
    if (g) {
      float* rp = red + ((g - 1) * ROWS + pt) * 3;
      rp[0] = a0; rp[1] = a1; rp[2] = a2;
    }
    __syncthreads();
    if (g == 0) {
      #pragma unroll 4
      for (int q = 0; q < GRP - 1; ++q) {
        const float* rp = red + (q * ROWS + pt) * 3;
        a0 += rp[0]; a1 += rp[1]; a2 += rp[2];
      }
      a0 *= INV_4PI_F; a1 *= INV_4PI_F; a2 *= INV_4PI_F;
      float* alpha = out + (size_t)7 * N;
      alpha[(size_t)row * 3 + 0] = a0;
      alpha[(size_t)row * 3 + 1] = a1;
      alpha[(size_t)row * 3 + 2] = a2;
      const float* dfp = dfsave + pt * 3;
      out[(size_t)N + (size_t)row * 3 + 0] = dfp[0] + a0;   // current = df + alpha
      out[(size_t)N + (size_t)row * 3 + 1] = dfp[1] + a1;
      out[(size_t)N + (size_t)row * 3 + 2] = dfp[2] + a2;
    }
  }
}

extern "C" void kernel_launch(void* const* d_in, const int* in_sizes, int n_in,
                              void* d_out, int out_size, void* d_ws, size_t ws_size,
                              hipStream_t stream) {
  const float* x    = (const float*)d_in[0];
  const float* bdry = (const float*)d_in[1];
  const float* Brff = (const float*)d_in[2];
  const float* W1   = (const float*)d_in[3];
  const float* b1   = (const float*)d_in[4];
  const float* W2   = (const float*)d_in[5];
  const float* b2   = (const float*)d_in[6];
  const float* W3   = (const float*)d_in[7];
  const float* b3   = (const float*)d_in[8];
  const float* W4   = (const float*)d_in[9];
  const float* b4   = (const float*)d_in[10];
  const float* W5   = (const float*)d_in[11];
  const float* b5   = (const float*)d_in[12];
  float* out = (float*)d_out;
  __bf16* ws = (__bf16*)d_ws;
  int N = in_sizes[0] / 3;   // 65536
  int M = in_sizes[1] / 3;   // 512

  k_prep<<<PACK_BLOCKS, 1024, 0, stream>>>(W1, W2, W3, W4, ws);

  size_t need = (size_t)(H_OFF + 3 * H_STRIDE) * sizeof(__bf16);  // ~103.5 MB
  if (ws_size >= need) {
    k_mlp<2><<<N / 128, 256, 0, stream>>>(x, Brff, bdry, b1, b2, b3, b4, W5, b5,
                                          ws, ws + H_OFF, out, N, M);
  } else {
    k_mlp<1><<<N / 64, 256, 0, stream>>>(x, Brff, bdry, b1, b2, b3, b4, W5, b5,
                                         ws, nullptr, out, N, M);
  }
}